// Round 1
// baseline (653.524 us; speedup 1.0000x reference)
//
#include <hip/hip_runtime.h>
#include <stdint.h>

#define NN 50000
#define NE 800000
#define H_OUT_OFF 6400000   // N*128, start of x_new in d_out

typedef float  f32x4  __attribute__((ext_vector_type(4)));
typedef short  bf16x8 __attribute__((ext_vector_type(8)));

static __device__ __forceinline__ unsigned short f2b(float f) {
  unsigned u = __float_as_uint(f);
  return (unsigned short)((u + 0x7fffu + ((u >> 16) & 1u)) >> 16);
}

// ---- prep: node f32 -> bf16 ----
__global__ void cvt_node_kernel(const float* __restrict__ node,
                                unsigned short* __restrict__ nodeb) {
  int i = blockIdx.x * 256 + threadIdx.x;  // one float4 per thread
  if (i < NN * 128 / 4) {
    float4 v = ((const float4*)node)[i];
    ushort4 o = make_ushort4(f2b(v.x), f2b(v.y), f2b(v.z), f2b(v.w));
    ((ushort4*)nodeb)[i] = o;
  }
}

// ---- prep: weights -> bf16, transposed to [n][k] (k contiguous) ----
__global__ void prep_weights_kernel(const float* __restrict__ We1,
                                    const float* __restrict__ We2,
                                    const float* __restrict__ Wh1,
                                    const float* __restrict__ Wh2,
                                    unsigned short* __restrict__ We1T,
                                    unsigned short* __restrict__ We2T,
                                    unsigned short* __restrict__ Wh1T,
                                    unsigned short* __restrict__ Wh2T) {
  int i = blockIdx.x * 256 + threadIdx.x;
  if (i < 32768) {                         // We1T [128][256] (rows 0..255 of We1)
    int n = i >> 8, k = i & 255;
    We1T[i] = f2b(We1[k * 128 + n]);
  } else if (i < 49152) {                  // We2T [128][128]
    int j = i - 32768; int n = j >> 7, k = j & 127;
    We2T[j] = f2b(We2[k * 128 + n]);
  } else if (i < 81920) {                  // Wh1T [128][256]
    int j = i - 49152; int n = j >> 8, k = j & 255;
    Wh1T[j] = f2b(Wh1[k * 128 + n]);
  } else if (i < 98304) {                  // Wh2T [128][128]
    int j = i - 81920; int n = j >> 7, k = j & 127;
    Wh2T[j] = f2b(Wh2[k * 128 + n]);
  }
}

// ---- edge kernel: 64 edges/block, 256 threads (4 waves) ----
// layer1: [64x256]@[256x128] MFMA (sqdist column as f32 rank-1 epilogue)
// layer2: [64x128]@[128x128] MFMA; w_ij via quad butterfly; atomics for m_i/delta
__global__ __launch_bounds__(256, 2)
void edge_kernel(const unsigned short* __restrict__ nodeb,
                 const float* __restrict__ coord,
                 const int* __restrict__ ei,          // [2][E]: src then dst
                 const unsigned short* __restrict__ We1T,
                 const float* __restrict__ We1,       // for sqdist row (row 256)
                 const float* __restrict__ be1,
                 const unsigned short* __restrict__ We2T,
                 const float* __restrict__ be2,
                 const float* __restrict__ Wx,
                 const float* __restrict__ bx,
                 float* __restrict__ m_agg,
                 float* __restrict__ delta) {
  __shared__ __align__(16) unsigned short sA[64][264];  // ein bf16, +8 pad
  __shared__ __align__(16) unsigned short sT[64][136];  // relu(l1) bf16, +8 pad
  __shared__ float sDist[64][3];
  __shared__ float sSq[64];
  __shared__ float sWp[64][4];
  __shared__ int   sDst[64];
  __shared__ int   sSrc[64];

  const int tid = threadIdx.x;
  const int e0 = blockIdx.x * 64;

  if (tid < 64) {
    int s_ = ei[e0 + tid];
    int d_ = ei[NE + e0 + tid];
    sSrc[tid] = s_;
    sDst[tid] = d_;
    float dx = coord[d_ * 3 + 0] - coord[s_ * 3 + 0];
    float dy = coord[d_ * 3 + 1] - coord[s_ * 3 + 1];
    float dz = coord[d_ * 3 + 2] - coord[s_ * 3 + 2];
    sDist[tid][0] = dx; sDist[tid][1] = dy; sDist[tid][2] = dz;
    sSq[tid] = dx * dx + dy * dy + dz * dz;
  }
  __syncthreads();

  // gather [h_i | h_j] into LDS, 16B chunks (32 chunks per 512B row)
  for (int c = tid; c < 64 * 32; c += 256) {
    int e = c >> 5, s = c & 31;
    int nidx = (s < 16) ? sDst[e] : sSrc[e];
    const uint4* p = (const uint4*)(nodeb + (size_t)nidx * 128) + (s & 15);
    *(uint4*)&sA[e][s * 8] = *p;
  }
  __syncthreads();

  const int wave = tid >> 6, lane = tid & 63;
  const int quad = lane >> 4, l16 = lane & 15;
  const int n0 = wave * 32;
  const int col0 = n0 + l16, col1 = n0 + 16 + l16;

  const f32x4 zero = {0.f, 0.f, 0.f, 0.f};
  f32x4 acc[4][2];
#pragma unroll
  for (int mt = 0; mt < 4; mt++) { acc[mt][0] = zero; acc[mt][1] = zero; }

  // ---- layer 1: K=256 ----
#pragma unroll
  for (int kt = 0; kt < 8; kt++) {
    int kb = kt * 32 + quad * 8;
    bf16x8 b0 = *(const bf16x8*)(We1T + (col0 << 8) + kb);
    bf16x8 b1 = *(const bf16x8*)(We1T + (col1 << 8) + kb);
#pragma unroll
    for (int mt = 0; mt < 4; mt++) {
      bf16x8 a = *(const bf16x8*)&sA[mt * 16 + l16][kb];
      acc[mt][0] = __builtin_amdgcn_mfma_f32_16x16x32_bf16(a, b0, acc[mt][0], 0, 0, 0);
      acc[mt][1] = __builtin_amdgcn_mfma_f32_16x16x32_bf16(a, b1, acc[mt][1], 0, 0, 0);
    }
  }

  // epilogue 1: + be1 + sqdist*We1[256][c], relu, -> sT (bf16)
  {
    float sb0 = be1[col0], sb1 = be1[col1];
    float sq0 = We1[256 * 128 + col0], sq1 = We1[256 * 128 + col1];
#pragma unroll
    for (int mt = 0; mt < 4; mt++) {
#pragma unroll
      for (int r = 0; r < 4; r++) {
        int row = mt * 16 + quad * 4 + r;
        float sq = sSq[row];
        float v0 = fmaxf(acc[mt][0][r] + sb0 + sq * sq0, 0.f);
        float v1 = fmaxf(acc[mt][1][r] + sb1 + sq * sq1, 0.f);
        sT[row][col0] = f2b(v0);
        sT[row][col1] = f2b(v1);
      }
    }
  }
  __syncthreads();

  // ---- layer 2: K=128 ----
  f32x4 acc2[4][2];
#pragma unroll
  for (int mt = 0; mt < 4; mt++) { acc2[mt][0] = zero; acc2[mt][1] = zero; }
#pragma unroll
  for (int kt = 0; kt < 4; kt++) {
    int kb = kt * 32 + quad * 8;
    bf16x8 b0 = *(const bf16x8*)(We2T + (col0 << 7) + kb);
    bf16x8 b1 = *(const bf16x8*)(We2T + (col1 << 7) + kb);
#pragma unroll
    for (int mt = 0; mt < 4; mt++) {
      bf16x8 a = *(const bf16x8*)&sT[mt * 16 + l16][kb];
      acc2[mt][0] = __builtin_amdgcn_mfma_f32_16x16x32_bf16(a, b0, acc2[mt][0], 0, 0, 0);
      acc2[mt][1] = __builtin_amdgcn_mfma_f32_16x16x32_bf16(a, b1, acc2[mt][1], 0, 0, 0);
    }
  }

  // epilogue 2: m = acc2+be2; atomic m_i; w partial via quad butterfly
  {
    float eb0 = be2[col0], eb1 = be2[col1];
    float wx0 = Wx[col0], wx1 = Wx[col1];
#pragma unroll
    for (int mt = 0; mt < 4; mt++) {
#pragma unroll
      for (int r = 0; r < 4; r++) {
        int row = mt * 16 + quad * 4 + r;
        int d_ = sDst[row];
        float m0 = acc2[mt][0][r] + eb0;
        float m1 = acc2[mt][1][r] + eb1;
        __hip_atomic_fetch_add(&m_agg[(size_t)d_ * 128 + col0], m0,
                               __ATOMIC_RELAXED, __HIP_MEMORY_SCOPE_AGENT);
        __hip_atomic_fetch_add(&m_agg[(size_t)d_ * 128 + col1], m1,
                               __ATOMIC_RELAXED, __HIP_MEMORY_SCOPE_AGENT);
        float pv = m0 * wx0 + m1 * wx1;
        pv += __shfl_xor(pv, 1, 16);
        pv += __shfl_xor(pv, 2, 16);
        pv += __shfl_xor(pv, 4, 16);
        pv += __shfl_xor(pv, 8, 16);
        if (l16 == 0) sWp[row][wave] = pv;
      }
    }
  }
  __syncthreads();

  if (tid < 64) {
    float w = sWp[tid][0] + sWp[tid][1] + sWp[tid][2] + sWp[tid][3] + bx[0];
    int d_ = sDst[tid];
    __hip_atomic_fetch_add(&delta[d_ * 3 + 0], sDist[tid][0] * w,
                           __ATOMIC_RELAXED, __HIP_MEMORY_SCOPE_AGENT);
    __hip_atomic_fetch_add(&delta[d_ * 3 + 1], sDist[tid][1] * w,
                           __ATOMIC_RELAXED, __HIP_MEMORY_SCOPE_AGENT);
    __hip_atomic_fetch_add(&delta[d_ * 3 + 2], sDist[tid][2] * w,
                           __ATOMIC_RELAXED, __HIP_MEMORY_SCOPE_AGENT);
  }
}

// ---- node kernel: 64 nodes/block; h_new + x_new ----
__global__ __launch_bounds__(256, 2)
void node_kernel(const unsigned short* __restrict__ nodeb,
                 const float* __restrict__ m_agg,
                 const unsigned short* __restrict__ Wh1T,
                 const float* __restrict__ bh1,
                 const unsigned short* __restrict__ Wh2T,
                 const float* __restrict__ bh2,
                 const float* __restrict__ coord,
                 const float* __restrict__ delta,
                 float* __restrict__ out) {
  __shared__ __align__(16) unsigned short sA[64][264];
  __shared__ __align__(16) unsigned short sT[64][136];

  const int tid = threadIdx.x;
  const int n0 = blockIdx.x * 64;

  // fused x_new (delta complete — edge kernel already done, stream order)
  {
    int i = blockIdx.x * 192 + tid;
    if (tid < 192 && i < NN * 3) {
      out[H_OUT_OFF + i] = coord[i] + (1.0f / 49999.0f) * delta[i];
    }
  }

  // stage [node | m_i] as bf16
  for (int c = tid; c < 64 * 32; c += 256) {
    int e = c >> 5, s = c & 31;
    int n = n0 + e;
    if (n < NN) {
      if (s < 16) {
        *(uint4*)&sA[e][s * 8] = *((const uint4*)(nodeb + (size_t)n * 128) + s);
      } else {
        const float* p = m_agg + (size_t)n * 128 + (size_t)(s - 16) * 8;
        float4 v0 = *(const float4*)p;
        float4 v1 = *(const float4*)(p + 4);
        *(ushort4*)&sA[e][s * 8]     = make_ushort4(f2b(v0.x), f2b(v0.y), f2b(v0.z), f2b(v0.w));
        *(ushort4*)&sA[e][s * 8 + 4] = make_ushort4(f2b(v1.x), f2b(v1.y), f2b(v1.z), f2b(v1.w));
      }
    } else {
      *(uint4*)&sA[e][s * 8] = make_uint4(0, 0, 0, 0);
    }
  }
  __syncthreads();

  const int wave = tid >> 6, lane = tid & 63;
  const int quad = lane >> 4, l16 = lane & 15;
  const int n0c = wave * 32;
  const int col0 = n0c + l16, col1 = n0c + 16 + l16;

  const f32x4 zero = {0.f, 0.f, 0.f, 0.f};
  f32x4 acc[4][2];
#pragma unroll
  for (int mt = 0; mt < 4; mt++) { acc[mt][0] = zero; acc[mt][1] = zero; }

#pragma unroll
  for (int kt = 0; kt < 8; kt++) {
    int kb = kt * 32 + quad * 8;
    bf16x8 b0 = *(const bf16x8*)(Wh1T + (col0 << 8) + kb);
    bf16x8 b1 = *(const bf16x8*)(Wh1T + (col1 << 8) + kb);
#pragma unroll
    for (int mt = 0; mt < 4; mt++) {
      bf16x8 a = *(const bf16x8*)&sA[mt * 16 + l16][kb];
      acc[mt][0] = __builtin_amdgcn_mfma_f32_16x16x32_bf16(a, b0, acc[mt][0], 0, 0, 0);
      acc[mt][1] = __builtin_amdgcn_mfma_f32_16x16x32_bf16(a, b1, acc[mt][1], 0, 0, 0);
    }
  }

  {
    float sb0 = bh1[col0], sb1 = bh1[col1];
#pragma unroll
    for (int mt = 0; mt < 4; mt++) {
#pragma unroll
      for (int r = 0; r < 4; r++) {
        int row = mt * 16 + quad * 4 + r;
        sT[row][col0] = f2b(fmaxf(acc[mt][0][r] + sb0, 0.f));
        sT[row][col1] = f2b(fmaxf(acc[mt][1][r] + sb1, 0.f));
      }
    }
  }
  __syncthreads();

  f32x4 acc2[4][2];
#pragma unroll
  for (int mt = 0; mt < 4; mt++) { acc2[mt][0] = zero; acc2[mt][1] = zero; }
#pragma unroll
  for (int kt = 0; kt < 4; kt++) {
    int kb = kt * 32 + quad * 8;
    bf16x8 b0 = *(const bf16x8*)(Wh2T + (col0 << 7) + kb);
    bf16x8 b1 = *(const bf16x8*)(Wh2T + (col1 << 7) + kb);
#pragma unroll
    for (int mt = 0; mt < 4; mt++) {
      bf16x8 a = *(const bf16x8*)&sT[mt * 16 + l16][kb];
      acc2[mt][0] = __builtin_amdgcn_mfma_f32_16x16x32_bf16(a, b0, acc2[mt][0], 0, 0, 0);
      acc2[mt][1] = __builtin_amdgcn_mfma_f32_16x16x32_bf16(a, b1, acc2[mt][1], 0, 0, 0);
    }
  }

  {
    float eb0 = bh2[col0], eb1 = bh2[col1];
#pragma unroll
    for (int mt = 0; mt < 4; mt++) {
#pragma unroll
      for (int r = 0; r < 4; r++) {
        int row = mt * 16 + quad * 4 + r;
        int n = n0 + row;
        if (n < NN) {
          out[(size_t)n * 128 + col0] = acc2[mt][0][r] + eb0;
          out[(size_t)n * 128 + col1] = acc2[mt][1][r] + eb1;
        }
      }
    }
  }
}

extern "C" void kernel_launch(void* const* d_in, const int* in_sizes, int n_in,
                              void* d_out, int out_size, void* d_ws, size_t ws_size,
                              hipStream_t stream) {
  const float* node  = (const float*)d_in[0];
  const float* coord = (const float*)d_in[1];
  const int*   ei    = (const int*)d_in[2];
  const float* We1   = (const float*)d_in[3];
  const float* be1   = (const float*)d_in[4];
  const float* We2   = (const float*)d_in[5];
  const float* be2   = (const float*)d_in[6];
  const float* Wx    = (const float*)d_in[7];
  const float* bx    = (const float*)d_in[8];
  const float* Wh1   = (const float*)d_in[9];
  const float* bh1   = (const float*)d_in[10];
  const float* Wh2   = (const float*)d_in[11];
  const float* bh2   = (const float*)d_in[12];
  float* out = (float*)d_out;

  char* ws = (char*)d_ws;
  float* m_agg = (float*)(ws);                               // 25,600,000 B
  float* delta = (float*)(ws + 25600000);                    //    600,000 B
  unsigned short* nodeb = (unsigned short*)(ws + 26200000);  // 12,800,000 B
  unsigned short* We1T  = (unsigned short*)(ws + 39000000);  //     65,536 B
  unsigned short* We2T  = (unsigned short*)(ws + 39065536);  //     32,768 B
  unsigned short* Wh1T  = (unsigned short*)(ws + 39098304);  //     65,536 B
  unsigned short* Wh2T  = (unsigned short*)(ws + 39163840);  //     32,768 B

  hipMemsetAsync(ws, 0, 26200000, stream);  // zero m_agg + delta

  cvt_node_kernel<<<6250, 256, 0, stream>>>(node, nodeb);
  prep_weights_kernel<<<384, 256, 0, stream>>>(We1, We2, Wh1, Wh2,
                                               We1T, We2T, Wh1T, Wh2T);
  edge_kernel<<<NE / 64, 256, 0, stream>>>(nodeb, coord, ei, We1T, We1, be1,
                                           We2T, be2, Wx, bx, m_agg, delta);
  node_kernel<<<(NN + 63) / 64, 256, 0, stream>>>(nodeb, m_agg, Wh1T, bh1,
                                                  Wh2T, bh2, coord, delta, out);
}

// Round 2
// 573.079 us; speedup vs baseline: 1.1404x; 1.1404x over previous
//
#include <hip/hip_runtime.h>
#include <stdint.h>

#define NN 50000
#define NE 800000
#define NBINS 50001          // dst bins + 1 pad slot so starts[50000] = NE
#define NPAD  50176          // 196*256
#define H_OUT_OFF 6400000    // N*128, start of x_new in d_out

typedef float  f32x4  __attribute__((ext_vector_type(4)));
typedef short  bf16x8 __attribute__((ext_vector_type(8)));

static __device__ __forceinline__ unsigned short f2b(float f) {
  unsigned u = __float_as_uint(f);
  return (unsigned short)((u + 0x7fffu + ((u >> 16) & 1u)) >> 16);
}

// ---- prep: node f32 -> bf16 ----
__global__ void cvt_node_kernel(const float* __restrict__ node,
                                unsigned short* __restrict__ nodeb) {
  int i = blockIdx.x * 256 + threadIdx.x;
  if (i < NN * 128 / 4) {
    float4 v = ((const float4*)node)[i];
    ((ushort4*)nodeb)[i] = make_ushort4(f2b(v.x), f2b(v.y), f2b(v.z), f2b(v.w));
  }
}

// ---- prep: weights -> bf16, transposed to [n][k] ----
__global__ void prep_weights_kernel(const float* __restrict__ We1,
                                    const float* __restrict__ We2,
                                    const float* __restrict__ Wh1,
                                    const float* __restrict__ Wh2,
                                    unsigned short* __restrict__ We1T,
                                    unsigned short* __restrict__ We2T,
                                    unsigned short* __restrict__ Wh1T,
                                    unsigned short* __restrict__ Wh2T) {
  int i = blockIdx.x * 256 + threadIdx.x;
  if (i < 32768) {
    int n = i >> 8, k = i & 255;
    We1T[i] = f2b(We1[k * 128 + n]);
  } else if (i < 49152) {
    int j = i - 32768; int n = j >> 7, k = j & 127;
    We2T[j] = f2b(We2[k * 128 + n]);
  } else if (i < 81920) {
    int j = i - 49152; int n = j >> 8, k = j & 255;
    Wh1T[j] = f2b(Wh1[k * 128 + n]);
  } else if (i < 98304) {
    int j = i - 81920; int n = j >> 7, k = j & 127;
    Wh2T[j] = f2b(Wh2[k * 128 + n]);
  }
}

// ---- counting sort of edges by dst ----
__global__ void hist_kernel(const int* __restrict__ ei, int* __restrict__ cnt) {
  int i = blockIdx.x * 256 + threadIdx.x;
  if (i < NE) atomicAdd(&cnt[ei[NE + i]], 1);
}

__global__ void scanA_kernel(const int* __restrict__ cnt, int* __restrict__ bsum) {
  __shared__ int sd[256];
  int b = blockIdx.x, t = threadIdx.x, i = b * 256 + t;
  sd[t] = (i < NBINS) ? cnt[i] : 0;
  __syncthreads();
  for (int s = 128; s; s >>= 1) {
    if (t < s) sd[t] += sd[t + s];
    __syncthreads();
  }
  if (t == 0) bsum[b] = sd[0];
}

__global__ void scanB_kernel(const int* __restrict__ bsum, int* __restrict__ boffs) {
  __shared__ int sd[256];
  int t = threadIdx.x;
  int v = (t < 196) ? bsum[t] : 0;
  sd[t] = v;
  __syncthreads();
  for (int off = 1; off < 256; off <<= 1) {
    int x = (t >= off) ? sd[t - off] : 0;
    __syncthreads();
    sd[t] += x;
    __syncthreads();
  }
  if (t < 196) boffs[t] = sd[t] - v;   // exclusive
}

__global__ void scanC_kernel(const int* __restrict__ cnt, const int* __restrict__ boffs,
                             int* __restrict__ starts, int* __restrict__ cursor) {
  __shared__ int sd[256];
  int b = blockIdx.x, t = threadIdx.x, i = b * 256 + t;
  int v = (i < NBINS) ? cnt[i] : 0;
  sd[t] = v;
  __syncthreads();
  for (int off = 1; off < 256; off <<= 1) {
    int x = (t >= off) ? sd[t - off] : 0;
    __syncthreads();
    sd[t] += x;
    __syncthreads();
  }
  int ex = sd[t] - v + boffs[b];       // exclusive global prefix
  if (i < NBINS) { starts[i] = ex; cursor[i] = ex; }
}

__global__ void scatter_kernel(const int* __restrict__ ei, int* __restrict__ cursor,
                               int* __restrict__ order) {
  int i = blockIdx.x * 256 + threadIdx.x;
  if (i < NE) {
    int d = ei[NE + i];
    int p = atomicAdd(&cursor[d], 1);
    order[p] = i;
  }
}

// ---- edge kernel: 64 sorted edges/block, 256 threads (4 waves) ----
__global__ __launch_bounds__(256, 2)
void edge_kernel(const unsigned short* __restrict__ nodeb,
                 const float* __restrict__ coord,
                 const int* __restrict__ ei,
                 const int* __restrict__ order,
                 const unsigned short* __restrict__ We1T,
                 const float* __restrict__ We1,
                 const float* __restrict__ be1,
                 const unsigned short* __restrict__ We2T,
                 const float* __restrict__ be2,
                 const float* __restrict__ Wx,
                 const float* __restrict__ bx,
                 float* __restrict__ m_agg,
                 float* __restrict__ delta) {
  __shared__ __align__(16) unsigned short sA[64][264];  // ein bf16; reused as f32 m [64][132]
  __shared__ __align__(16) unsigned short sT[64][136];  // relu(l1) bf16
  __shared__ float sDist[64][3];
  __shared__ float sSq[64];
  __shared__ float sWp[64][4];
  __shared__ float sVec[64][3];
  __shared__ int   sDst[64];
  __shared__ int   sSrc[64];
  __shared__ int   sSegList[64];
  __shared__ int   sNseg;

  float* sAf = (float*)&sA[0][0];     // [64][132] view (33792 B, exact alias)

  const int tid = threadIdx.x;
  const int e0 = blockIdx.x * 64;

  if (tid < 64) {
    int e  = order[e0 + tid];         // sorted-by-dst edge id
    int s_ = ei[e];
    int d_ = ei[NE + e];
    sSrc[tid] = s_;
    sDst[tid] = d_;
    float dx = coord[d_ * 3 + 0] - coord[s_ * 3 + 0];
    float dy = coord[d_ * 3 + 1] - coord[s_ * 3 + 1];
    float dz = coord[d_ * 3 + 2] - coord[s_ * 3 + 2];
    sDist[tid][0] = dx; sDist[tid][1] = dy; sDist[tid][2] = dz;
    sSq[tid] = dx * dx + dy * dy + dz * dz;
  }
  __syncthreads();

  // segment metadata (wave 0 only; dst sorted within block)
  if (tid < 64) {
    int flag = (tid == 0) || (sDst[tid] != sDst[tid - 1]);
    unsigned long long mask = __ballot(flag);
    if (flag) {
      int r = __popcll(mask & ((1ull << tid) - 1ull));
      sSegList[r] = tid;
    }
    if (tid == 0) sNseg = __popcll(mask);
  }

  // gather [h_i | h_j] bf16 into LDS (sorted dst -> heavy L1 reuse on h_i)
  for (int c = tid; c < 64 * 32; c += 256) {
    int e = c >> 5, s = c & 31;
    int nidx = (s < 16) ? sDst[e] : sSrc[e];
    *(uint4*)&sA[e][s * 8] = *((const uint4*)(nodeb + (size_t)nidx * 128) + (s & 15));
  }
  __syncthreads();

  const int wave = tid >> 6, lane = tid & 63;
  const int quad = lane >> 4, l16 = lane & 15;
  const int col0 = wave * 32 + l16, col1 = wave * 32 + 16 + l16;

  const f32x4 zero = {0.f, 0.f, 0.f, 0.f};
  f32x4 acc[4][2];
#pragma unroll
  for (int mt = 0; mt < 4; mt++) { acc[mt][0] = zero; acc[mt][1] = zero; }

  // ---- layer 1: K=256 ----
#pragma unroll
  for (int kt = 0; kt < 8; kt++) {
    int kb = kt * 32 + quad * 8;
    bf16x8 b0 = *(const bf16x8*)(We1T + (col0 << 8) + kb);
    bf16x8 b1 = *(const bf16x8*)(We1T + (col1 << 8) + kb);
#pragma unroll
    for (int mt = 0; mt < 4; mt++) {
      bf16x8 a = *(const bf16x8*)&sA[mt * 16 + l16][kb];
      acc[mt][0] = __builtin_amdgcn_mfma_f32_16x16x32_bf16(a, b0, acc[mt][0], 0, 0, 0);
      acc[mt][1] = __builtin_amdgcn_mfma_f32_16x16x32_bf16(a, b1, acc[mt][1], 0, 0, 0);
    }
  }

  // epilogue 1: + be1 + sqdist*We1[256][c], relu -> sT bf16
  {
    float sb0 = be1[col0], sb1 = be1[col1];
    float sq0 = We1[256 * 128 + col0], sq1 = We1[256 * 128 + col1];
#pragma unroll
    for (int mt = 0; mt < 4; mt++) {
#pragma unroll
      for (int r = 0; r < 4; r++) {
        int row = mt * 16 + quad * 4 + r;
        float sq = sSq[row];
        sT[row][col0] = f2b(fmaxf(acc[mt][0][r] + sb0 + sq * sq0, 0.f));
        sT[row][col1] = f2b(fmaxf(acc[mt][1][r] + sb1 + sq * sq1, 0.f));
      }
    }
  }
  __syncthreads();

  // ---- layer 2: K=128 ----
  f32x4 acc2[4][2];
#pragma unroll
  for (int mt = 0; mt < 4; mt++) { acc2[mt][0] = zero; acc2[mt][1] = zero; }
#pragma unroll
  for (int kt = 0; kt < 4; kt++) {
    int kb = kt * 32 + quad * 8;
    bf16x8 b0 = *(const bf16x8*)(We2T + (col0 << 7) + kb);
    bf16x8 b1 = *(const bf16x8*)(We2T + (col1 << 7) + kb);
#pragma unroll
    for (int mt = 0; mt < 4; mt++) {
      bf16x8 a = *(const bf16x8*)&sT[mt * 16 + l16][kb];
      acc2[mt][0] = __builtin_amdgcn_mfma_f32_16x16x32_bf16(a, b0, acc2[mt][0], 0, 0, 0);
      acc2[mt][1] = __builtin_amdgcn_mfma_f32_16x16x32_bf16(a, b1, acc2[mt][1], 0, 0, 0);
    }
  }

  // epilogue 2: m = acc2+be2 -> LDS f32 (sA reused); pv butterfly for w
  {
    float eb0 = be2[col0], eb1 = be2[col1];
    float wx0 = Wx[col0], wx1 = Wx[col1];
#pragma unroll
    for (int mt = 0; mt < 4; mt++) {
#pragma unroll
      for (int r = 0; r < 4; r++) {
        int row = mt * 16 + quad * 4 + r;
        float m0 = acc2[mt][0][r] + eb0;
        float m1 = acc2[mt][1][r] + eb1;
        sAf[row * 132 + col0] = m0;
        sAf[row * 132 + col1] = m1;
        float pv = m0 * wx0 + m1 * wx1;
        pv += __shfl_xor(pv, 1, 16);
        pv += __shfl_xor(pv, 2, 16);
        pv += __shfl_xor(pv, 4, 16);
        pv += __shfl_xor(pv, 8, 16);
        if (l16 == 0) sWp[row][wave] = pv;
      }
    }
  }
  __syncthreads();

  // per-edge w and vec = dist*w
  if (tid < 64) {
    float w_ = sWp[tid][0] + sWp[tid][1] + sWp[tid][2] + sWp[tid][3] + bx[0];
    sVec[tid][0] = sDist[tid][0] * w_;
    sVec[tid][1] = sDist[tid][1] * w_;
    sVec[tid][2] = sDist[tid][2] * w_;
  }

  // segmented pre-reduction of m: one atomic set per distinct dst in block
  {
    int nseg = sNseg;
    for (int s = wave; s < nseg; s += 4) {
      int a  = sSegList[s];
      int b  = (s + 1 < nseg) ? sSegList[s + 1] : 64;
      int d_ = sDst[a];
      float s0 = 0.f, s1 = 0.f;
      for (int r = a; r < b; r++) {
        float2 v = *(const float2*)&sAf[r * 132 + 2 * lane];
        s0 += v.x; s1 += v.y;
      }
      atomicAdd(&m_agg[(size_t)d_ * 128 + 2 * lane],     s0);
      atomicAdd(&m_agg[(size_t)d_ * 128 + 2 * lane + 1], s1);
    }
  }
  __syncthreads();

  // segmented pre-reduction of delta
  if (tid < sNseg) {
    int a  = sSegList[tid];
    int b  = (tid + 1 < sNseg) ? sSegList[tid + 1] : 64;
    int d_ = sDst[a];
    float vx = 0.f, vy = 0.f, vz = 0.f;
    for (int r = a; r < b; r++) {
      vx += sVec[r][0]; vy += sVec[r][1]; vz += sVec[r][2];
    }
    atomicAdd(&delta[d_ * 3 + 0], vx);
    atomicAdd(&delta[d_ * 3 + 1], vy);
    atomicAdd(&delta[d_ * 3 + 2], vz);
  }
}

// ---- node kernel: 64 nodes/block; h_new + x_new ----
__global__ __launch_bounds__(256, 2)
void node_kernel(const unsigned short* __restrict__ nodeb,
                 const float* __restrict__ m_agg,
                 const unsigned short* __restrict__ Wh1T,
                 const float* __restrict__ bh1,
                 const unsigned short* __restrict__ Wh2T,
                 const float* __restrict__ bh2,
                 const float* __restrict__ coord,
                 const float* __restrict__ delta,
                 float* __restrict__ out) {
  __shared__ __align__(16) unsigned short sA[64][264];
  __shared__ __align__(16) unsigned short sT[64][136];

  const int tid = threadIdx.x;
  const int n0 = blockIdx.x * 64;

  {
    int i = blockIdx.x * 192 + tid;
    if (tid < 192 && i < NN * 3) {
      out[H_OUT_OFF + i] = coord[i] + (1.0f / 49999.0f) * delta[i];
    }
  }

  for (int c = tid; c < 64 * 32; c += 256) {
    int e = c >> 5, s = c & 31;
    int n = n0 + e;
    if (n < NN) {
      if (s < 16) {
        *(uint4*)&sA[e][s * 8] = *((const uint4*)(nodeb + (size_t)n * 128) + s);
      } else {
        const float* p = m_agg + (size_t)n * 128 + (size_t)(s - 16) * 8;
        float4 v0 = *(const float4*)p;
        float4 v1 = *(const float4*)(p + 4);
        *(ushort4*)&sA[e][s * 8]     = make_ushort4(f2b(v0.x), f2b(v0.y), f2b(v0.z), f2b(v0.w));
        *(ushort4*)&sA[e][s * 8 + 4] = make_ushort4(f2b(v1.x), f2b(v1.y), f2b(v1.z), f2b(v1.w));
      }
    } else {
      *(uint4*)&sA[e][s * 8] = make_uint4(0, 0, 0, 0);
    }
  }
  __syncthreads();

  const int wave = tid >> 6, lane = tid & 63;
  const int quad = lane >> 4, l16 = lane & 15;
  const int col0 = wave * 32 + l16, col1 = wave * 32 + 16 + l16;

  const f32x4 zero = {0.f, 0.f, 0.f, 0.f};
  f32x4 acc[4][2];
#pragma unroll
  for (int mt = 0; mt < 4; mt++) { acc[mt][0] = zero; acc[mt][1] = zero; }

#pragma unroll
  for (int kt = 0; kt < 8; kt++) {
    int kb = kt * 32 + quad * 8;
    bf16x8 b0 = *(const bf16x8*)(Wh1T + (col0 << 8) + kb);
    bf16x8 b1 = *(const bf16x8*)(Wh1T + (col1 << 8) + kb);
#pragma unroll
    for (int mt = 0; mt < 4; mt++) {
      bf16x8 a = *(const bf16x8*)&sA[mt * 16 + l16][kb];
      acc[mt][0] = __builtin_amdgcn_mfma_f32_16x16x32_bf16(a, b0, acc[mt][0], 0, 0, 0);
      acc[mt][1] = __builtin_amdgcn_mfma_f32_16x16x32_bf16(a, b1, acc[mt][1], 0, 0, 0);
    }
  }

  {
    float sb0 = bh1[col0], sb1 = bh1[col1];
#pragma unroll
    for (int mt = 0; mt < 4; mt++) {
#pragma unroll
      for (int r = 0; r < 4; r++) {
        int row = mt * 16 + quad * 4 + r;
        sT[row][col0] = f2b(fmaxf(acc[mt][0][r] + sb0, 0.f));
        sT[row][col1] = f2b(fmaxf(acc[mt][1][r] + sb1, 0.f));
      }
    }
  }
  __syncthreads();

  f32x4 acc2[4][2];
#pragma unroll
  for (int mt = 0; mt < 4; mt++) { acc2[mt][0] = zero; acc2[mt][1] = zero; }
#pragma unroll
  for (int kt = 0; kt < 4; kt++) {
    int kb = kt * 32 + quad * 8;
    bf16x8 b0 = *(const bf16x8*)(Wh2T + (col0 << 7) + kb);
    bf16x8 b1 = *(const bf16x8*)(Wh2T + (col1 << 7) + kb);
#pragma unroll
    for (int mt = 0; mt < 4; mt++) {
      bf16x8 a = *(const bf16x8*)&sT[mt * 16 + l16][kb];
      acc2[mt][0] = __builtin_amdgcn_mfma_f32_16x16x32_bf16(a, b0, acc2[mt][0], 0, 0, 0);
      acc2[mt][1] = __builtin_amdgcn_mfma_f32_16x16x32_bf16(a, b1, acc2[mt][1], 0, 0, 0);
    }
  }

  {
    float eb0 = bh2[col0], eb1 = bh2[col1];
#pragma unroll
    for (int mt = 0; mt < 4; mt++) {
#pragma unroll
      for (int r = 0; r < 4; r++) {
        int row = mt * 16 + quad * 4 + r;
        int n = n0 + row;
        if (n < NN) {
          out[(size_t)n * 128 + col0] = acc2[mt][0][r] + eb0;
          out[(size_t)n * 128 + col1] = acc2[mt][1][r] + eb1;
        }
      }
    }
  }
}

extern "C" void kernel_launch(void* const* d_in, const int* in_sizes, int n_in,
                              void* d_out, int out_size, void* d_ws, size_t ws_size,
                              hipStream_t stream) {
  const float* node  = (const float*)d_in[0];
  const float* coord = (const float*)d_in[1];
  const int*   ei    = (const int*)d_in[2];
  const float* We1   = (const float*)d_in[3];
  const float* be1   = (const float*)d_in[4];
  const float* We2   = (const float*)d_in[5];
  const float* be2   = (const float*)d_in[6];
  const float* Wx    = (const float*)d_in[7];
  const float* bx    = (const float*)d_in[8];
  const float* Wh1   = (const float*)d_in[9];
  const float* bh1   = (const float*)d_in[10];
  const float* Wh2   = (const float*)d_in[11];
  const float* bh2   = (const float*)d_in[12];
  float* out = (float*)d_out;

  char* ws = (char*)d_ws;
  float* m_agg   = (float*)(ws);                     // 25,600,000
  float* delta   = (float*)(ws + 25600000);          //    600,000
  int*   cnt     = (int*)  (ws + 26200000);          //    200,704 (NPAD*4)
  int*   starts  = (int*)  (ws + 26400704);          //    200,704
  int*   cursor  = (int*)  (ws + 26601408);          //    200,704
  int*   bsum    = (int*)  (ws + 26802112);          //      1,024
  int*   boffs   = (int*)  (ws + 26803136);          //      1,024
  int*   order   = (int*)  (ws + 26804160);          //  3,200,000
  unsigned short* nodeb = (unsigned short*)(ws + 30004160); // 12,800,000
  unsigned short* We1T  = (unsigned short*)(ws + 42804160); //     65,536
  unsigned short* We2T  = (unsigned short*)(ws + 42869696); //     32,768
  unsigned short* Wh1T  = (unsigned short*)(ws + 42902464); //     65,536
  unsigned short* Wh2T  = (unsigned short*)(ws + 42968000); //     32,768

  hipMemsetAsync(ws, 0, 26400704, stream);  // m_agg + delta + cnt

  cvt_node_kernel<<<6250, 256, 0, stream>>>(node, nodeb);
  prep_weights_kernel<<<384, 256, 0, stream>>>(We1, We2, Wh1, Wh2,
                                               We1T, We2T, Wh1T, Wh2T);
  hist_kernel<<<3125, 256, 0, stream>>>(ei, cnt);
  scanA_kernel<<<196, 256, 0, stream>>>(cnt, bsum);
  scanB_kernel<<<1, 256, 0, stream>>>(bsum, boffs);
  scanC_kernel<<<196, 256, 0, stream>>>(cnt, boffs, starts, cursor);
  scatter_kernel<<<3125, 256, 0, stream>>>(ei, cursor, order);
  edge_kernel<<<NE / 64, 256, 0, stream>>>(nodeb, coord, ei, order, We1T, We1, be1,
                                           We2T, be2, Wx, bx, m_agg, delta);
  node_kernel<<<(NN + 63) / 64, 256, 0, stream>>>(nodeb, m_agg, Wh1T, bh1,
                                                  Wh2T, bh2, coord, delta, out);
}

// Round 3
// 395.488 us; speedup vs baseline: 1.6524x; 1.4490x over previous
//
#include <hip/hip_runtime.h>
#include <stdint.h>

#define NN 50000
#define NE 800000
#define NBINS 50001          // dst bins + 1 pad slot
#define H_OUT_OFF 6400000    // N*128, start of x_new in d_out

typedef float  f32x4  __attribute__((ext_vector_type(4)));
typedef short  bf16x8 __attribute__((ext_vector_type(8)));

static __device__ __forceinline__ unsigned short f2b(float f) {
  unsigned u = __float_as_uint(f);
  return (unsigned short)((u + 0x7fffu + ((u >> 16) & 1u)) >> 16);
}
static __device__ __forceinline__ float b2f(unsigned short h) {
  return __uint_as_float(((unsigned)h) << 16);
}

// ---- prep: node f32 -> bf16 ----
__global__ void cvt_node_kernel(const float* __restrict__ node,
                                unsigned short* __restrict__ nodeb) {
  int i = blockIdx.x * 256 + threadIdx.x;
  if (i < NN * 128 / 4) {
    float4 v = ((const float4*)node)[i];
    ((ushort4*)nodeb)[i] = make_ushort4(f2b(v.x), f2b(v.y), f2b(v.z), f2b(v.w));
  }
}

// ---- prep: weights -> bf16 transposed [n][k] ----
__global__ void prep_weights_kernel(const float* __restrict__ We1,
                                    const float* __restrict__ We2,
                                    const float* __restrict__ Wh1,
                                    const float* __restrict__ Wh2,
                                    unsigned short* __restrict__ We1Ttop,
                                    unsigned short* __restrict__ We1Tbot,
                                    unsigned short* __restrict__ We2T,
                                    unsigned short* __restrict__ Wh1T,
                                    unsigned short* __restrict__ Wh2T) {
  int i = blockIdx.x * 256 + threadIdx.x;
  if (i < 16384) {                       // We1Ttop [128n][128k], k = h_i dims
    int n = i >> 7, k = i & 127;
    We1Ttop[i] = f2b(We1[k * 128 + n]);
  } else if (i < 32768) {                // We1Tbot, k = h_j dims (rows 128..255)
    int j = i - 16384; int n = j >> 7, k = j & 127;
    We1Tbot[j] = f2b(We1[(128 + k) * 128 + n]);
  } else if (i < 49152) {                // We2T [128][128]
    int j = i - 32768; int n = j >> 7, k = j & 127;
    We2T[j] = f2b(We2[k * 128 + n]);
  } else if (i < 81920) {                // Wh1T [128][256]
    int j = i - 49152; int n = j >> 8, k = j & 255;
    Wh1T[j] = f2b(Wh1[k * 128 + n]);
  } else if (i < 98304) {                // Wh2T [128][128]
    int j = i - 81920; int n = j >> 7, k = j & 127;
    Wh2T[j] = f2b(Wh2[k * 128 + n]);
  }
}

// ---- counting sort of edges by dst (hist returns per-edge rank) ----
__global__ void hist_kernel(const int* __restrict__ ei, int* __restrict__ cnt,
                            int* __restrict__ rank) {
  int i = blockIdx.x * 256 + threadIdx.x;
  if (i < NE) rank[i] = atomicAdd(&cnt[ei[NE + i]], 1);
}

__global__ void scanA_kernel(const int* __restrict__ cnt, int* __restrict__ bsum) {
  __shared__ int sd[256];
  int b = blockIdx.x, t = threadIdx.x, i = b * 256 + t;
  sd[t] = (i < NBINS) ? cnt[i] : 0;
  __syncthreads();
  for (int s = 128; s; s >>= 1) {
    if (t < s) sd[t] += sd[t + s];
    __syncthreads();
  }
  if (t == 0) bsum[b] = sd[0];
}

__global__ void scanB_kernel(const int* __restrict__ bsum, int* __restrict__ boffs) {
  __shared__ int sd[256];
  int t = threadIdx.x;
  int v = (t < 196) ? bsum[t] : 0;
  sd[t] = v;
  __syncthreads();
  for (int off = 1; off < 256; off <<= 1) {
    int x = (t >= off) ? sd[t - off] : 0;
    __syncthreads();
    sd[t] += x;
    __syncthreads();
  }
  if (t < 196) boffs[t] = sd[t] - v;   // exclusive
}

__global__ void scanC_kernel(const int* __restrict__ cnt, const int* __restrict__ boffs,
                             int* __restrict__ starts) {
  __shared__ int sd[256];
  int b = blockIdx.x, t = threadIdx.x, i = b * 256 + t;
  int v = (i < NBINS) ? cnt[i] : 0;
  sd[t] = v;
  __syncthreads();
  for (int off = 1; off < 256; off <<= 1) {
    int x = (t >= off) ? sd[t - off] : 0;
    __syncthreads();
    sd[t] += x;
    __syncthreads();
  }
  if (i < NBINS) starts[i] = sd[t] - v + boffs[b];
}

__global__ void scatter_kernel(const int* __restrict__ ei, const int* __restrict__ starts,
                               const int* __restrict__ rank, int* __restrict__ order) {
  int i = blockIdx.x * 256 + threadIdx.x;
  if (i < NE) {
    int d = ei[NE + i];
    order[starts[d] + rank[i]] = i;
  }
}

// ---- Y = node @ We1_top + be1, bf16 output ----
__global__ __launch_bounds__(256, 4)
void y_kernel(const unsigned short* __restrict__ nodeb,
              const unsigned short* __restrict__ We1Ttop,
              const float* __restrict__ be1,
              unsigned short* __restrict__ Yb) {
  __shared__ __align__(16) unsigned short sA[64][136];
  const int tid = threadIdx.x;
  const int n0 = blockIdx.x * 64;

  for (int c = tid; c < 64 * 16; c += 256) {
    int e = c >> 4, s = c & 15;
    int n = n0 + e;
    if (n < NN) *(uint4*)&sA[e][s * 8] = *((const uint4*)(nodeb + (size_t)n * 128) + s);
    else        *(uint4*)&sA[e][s * 8] = make_uint4(0, 0, 0, 0);
  }
  __syncthreads();

  const int wave = tid >> 6, lane = tid & 63;
  const int quad = lane >> 4, l16 = lane & 15;
  const int col0 = wave * 32 + l16, col1 = wave * 32 + 16 + l16;

  const f32x4 zero = {0.f, 0.f, 0.f, 0.f};
  f32x4 acc[4][2];
#pragma unroll
  for (int mt = 0; mt < 4; mt++) { acc[mt][0] = zero; acc[mt][1] = zero; }

#pragma unroll
  for (int kt = 0; kt < 4; kt++) {
    int kb = kt * 32 + quad * 8;
    bf16x8 b0 = *(const bf16x8*)(We1Ttop + (col0 << 7) + kb);
    bf16x8 b1 = *(const bf16x8*)(We1Ttop + (col1 << 7) + kb);
#pragma unroll
    for (int mt = 0; mt < 4; mt++) {
      bf16x8 a = *(const bf16x8*)&sA[mt * 16 + l16][kb];
      acc[mt][0] = __builtin_amdgcn_mfma_f32_16x16x32_bf16(a, b0, acc[mt][0], 0, 0, 0);
      acc[mt][1] = __builtin_amdgcn_mfma_f32_16x16x32_bf16(a, b1, acc[mt][1], 0, 0, 0);
    }
  }

  float sb0 = be1[col0], sb1 = be1[col1];
#pragma unroll
  for (int mt = 0; mt < 4; mt++) {
#pragma unroll
    for (int r = 0; r < 4; r++) {
      int row = mt * 16 + quad * 4 + r;
      int n = n0 + row;
      if (n < NN) {
        Yb[(size_t)n * 128 + col0] = f2b(acc[mt][0][r] + sb0);
        Yb[(size_t)n * 128 + col1] = f2b(acc[mt][1][r] + sb1);
      }
    }
  }
}

// ---- edge kernel: 64 sorted edges/block, 256 threads, 4 blocks/CU ----
__global__ __launch_bounds__(256, 4)
void edge_kernel(const unsigned short* __restrict__ nodeb,
                 const float* __restrict__ coord,
                 const int* __restrict__ ei,
                 const int* __restrict__ order,
                 const unsigned short* __restrict__ We1Tbot,
                 const float* __restrict__ We1,      // row 256 (sqdist weights)
                 const unsigned short* __restrict__ Yb,
                 const unsigned short* __restrict__ We2T,
                 const float* __restrict__ be2,
                 const float* __restrict__ Wx,
                 const float* __restrict__ bx,
                 float* __restrict__ m_agg,
                 float* __restrict__ delta) {
  __shared__ __align__(16) unsigned short sA[64][136];  // h_j bf16; reused for m bf16
  __shared__ __align__(16) unsigned short sT[64][136];  // relu(l1) bf16
  __shared__ float sDist[64][3];
  __shared__ float sSq[64];
  __shared__ float sWp[64][4];
  __shared__ float sVec[64][3];
  __shared__ int   sDst[64];
  __shared__ int   sSrc[64];
  __shared__ int   sSegList[64];
  __shared__ int   sNseg;

  const int tid = threadIdx.x;
  const int e0 = blockIdx.x * 64;

  if (tid < 64) {
    int e  = order[e0 + tid];
    int s_ = ei[e];
    int d_ = ei[NE + e];
    sSrc[tid] = s_;
    sDst[tid] = d_;
    float dx = coord[d_ * 3 + 0] - coord[s_ * 3 + 0];
    float dy = coord[d_ * 3 + 1] - coord[s_ * 3 + 1];
    float dz = coord[d_ * 3 + 2] - coord[s_ * 3 + 2];
    sDist[tid][0] = dx; sDist[tid][1] = dy; sDist[tid][2] = dz;
    sSq[tid] = dx * dx + dy * dy + dz * dz;
  }
  __syncthreads();

  if (tid < 64) {
    int flag = (tid == 0) || (sDst[tid] != sDst[tid - 1]);
    unsigned long long mask = __ballot(flag);
    if (flag) {
      int r = __popcll(mask & ((1ull << tid) - 1ull));
      sSegList[r] = tid;
    }
    if (tid == 0) sNseg = __popcll(mask);
  }

  // gather h_j only (src random; dst handled via precomputed Y)
  for (int c = tid; c < 64 * 16; c += 256) {
    int e = c >> 4, s = c & 15;
    *(uint4*)&sA[e][s * 8] = *((const uint4*)(nodeb + (size_t)sSrc[e] * 128) + s);
  }
  __syncthreads();

  const int wave = tid >> 6, lane = tid & 63;
  const int quad = lane >> 4, l16 = lane & 15;
  const int col0 = wave * 32 + l16, col1 = wave * 32 + 16 + l16;

  const f32x4 zero = {0.f, 0.f, 0.f, 0.f};
  f32x4 acc[4][2];
#pragma unroll
  for (int mt = 0; mt < 4; mt++) { acc[mt][0] = zero; acc[mt][1] = zero; }

  // ---- layer 1: h_j @ We1_bot, K=128 ----
#pragma unroll
  for (int kt = 0; kt < 4; kt++) {
    int kb = kt * 32 + quad * 8;
    bf16x8 b0 = *(const bf16x8*)(We1Tbot + (col0 << 7) + kb);
    bf16x8 b1 = *(const bf16x8*)(We1Tbot + (col1 << 7) + kb);
#pragma unroll
    for (int mt = 0; mt < 4; mt++) {
      bf16x8 a = *(const bf16x8*)&sA[mt * 16 + l16][kb];
      acc[mt][0] = __builtin_amdgcn_mfma_f32_16x16x32_bf16(a, b0, acc[mt][0], 0, 0, 0);
      acc[mt][1] = __builtin_amdgcn_mfma_f32_16x16x32_bf16(a, b1, acc[mt][1], 0, 0, 0);
    }
  }

  // epilogue 1: + Y[dst] + sqdist*We1[256], relu -> sT bf16
  {
    float sq0 = We1[256 * 128 + col0], sq1 = We1[256 * 128 + col1];
#pragma unroll
    for (int mt = 0; mt < 4; mt++) {
#pragma unroll
      for (int r = 0; r < 4; r++) {
        int row = mt * 16 + quad * 4 + r;
        float sq = sSq[row];
        int d_ = sDst[row];
        float y0 = b2f(Yb[(size_t)d_ * 128 + col0]);
        float y1 = b2f(Yb[(size_t)d_ * 128 + col1]);
        sT[row][col0] = f2b(fmaxf(acc[mt][0][r] + y0 + sq * sq0, 0.f));
        sT[row][col1] = f2b(fmaxf(acc[mt][1][r] + y1 + sq * sq1, 0.f));
      }
    }
  }
  __syncthreads();

  // ---- layer 2: K=128 ----
  f32x4 acc2[4][2];
#pragma unroll
  for (int mt = 0; mt < 4; mt++) { acc2[mt][0] = zero; acc2[mt][1] = zero; }
#pragma unroll
  for (int kt = 0; kt < 4; kt++) {
    int kb = kt * 32 + quad * 8;
    bf16x8 b0 = *(const bf16x8*)(We2T + (col0 << 7) + kb);
    bf16x8 b1 = *(const bf16x8*)(We2T + (col1 << 7) + kb);
#pragma unroll
    for (int mt = 0; mt < 4; mt++) {
      bf16x8 a = *(const bf16x8*)&sT[mt * 16 + l16][kb];
      acc2[mt][0] = __builtin_amdgcn_mfma_f32_16x16x32_bf16(a, b0, acc2[mt][0], 0, 0, 0);
      acc2[mt][1] = __builtin_amdgcn_mfma_f32_16x16x32_bf16(a, b1, acc2[mt][1], 0, 0, 0);
    }
  }

  // epilogue 2: m = acc2+be2 -> sA as bf16; pv butterfly for w
  {
    float eb0 = be2[col0], eb1 = be2[col1];
    float wx0 = Wx[col0], wx1 = Wx[col1];
#pragma unroll
    for (int mt = 0; mt < 4; mt++) {
#pragma unroll
      for (int r = 0; r < 4; r++) {
        int row = mt * 16 + quad * 4 + r;
        float m0 = acc2[mt][0][r] + eb0;
        float m1 = acc2[mt][1][r] + eb1;
        sA[row][col0] = f2b(m0);
        sA[row][col1] = f2b(m1);
        float pv = m0 * wx0 + m1 * wx1;
        pv += __shfl_xor(pv, 1, 16);
        pv += __shfl_xor(pv, 2, 16);
        pv += __shfl_xor(pv, 4, 16);
        pv += __shfl_xor(pv, 8, 16);
        if (l16 == 0) sWp[row][wave] = pv;
      }
    }
  }
  __syncthreads();

  if (tid < 64) {
    float w_ = sWp[tid][0] + sWp[tid][1] + sWp[tid][2] + sWp[tid][3] + bx[0];
    sVec[tid][0] = sDist[tid][0] * w_;
    sVec[tid][1] = sDist[tid][1] * w_;
    sVec[tid][2] = sDist[tid][2] * w_;
  }

  // segmented pre-reduction of m (bf16 read, f32 accumulate): one atomic set per dst
  {
    int nseg = sNseg;
    for (int s = wave; s < nseg; s += 4) {
      int a  = sSegList[s];
      int b  = (s + 1 < nseg) ? sSegList[s + 1] : 64;
      int d_ = sDst[a];
      float s0 = 0.f, s1 = 0.f;
      for (int r = a; r < b; r++) {
        ushort2 v = *(const ushort2*)&sA[r][2 * lane];
        s0 += b2f(v.x); s1 += b2f(v.y);
      }
      atomicAdd(&m_agg[(size_t)d_ * 128 + 2 * lane],     s0);
      atomicAdd(&m_agg[(size_t)d_ * 128 + 2 * lane + 1], s1);
    }
  }
  __syncthreads();

  if (tid < sNseg) {
    int a  = sSegList[tid];
    int b  = (tid + 1 < sNseg) ? sSegList[tid + 1] : 64;
    int d_ = sDst[a];
    float vx = 0.f, vy = 0.f, vz = 0.f;
    for (int r = a; r < b; r++) {
      vx += sVec[r][0]; vy += sVec[r][1]; vz += sVec[r][2];
    }
    atomicAdd(&delta[d_ * 3 + 0], vx);
    atomicAdd(&delta[d_ * 3 + 1], vy);
    atomicAdd(&delta[d_ * 3 + 2], vz);
  }
}

// ---- node kernel: 64 nodes/block; h_new + x_new ----
__global__ __launch_bounds__(256, 3)
void node_kernel(const unsigned short* __restrict__ nodeb,
                 const float* __restrict__ m_agg,
                 const unsigned short* __restrict__ Wh1T,
                 const float* __restrict__ bh1,
                 const unsigned short* __restrict__ Wh2T,
                 const float* __restrict__ bh2,
                 const float* __restrict__ coord,
                 const float* __restrict__ delta,
                 float* __restrict__ out) {
  __shared__ __align__(16) unsigned short sA[64][264];
  __shared__ __align__(16) unsigned short sT[64][136];

  const int tid = threadIdx.x;
  const int n0 = blockIdx.x * 64;

  {
    int i = blockIdx.x * 192 + tid;
    if (tid < 192 && i < NN * 3) {
      out[H_OUT_OFF + i] = coord[i] + (1.0f / 49999.0f) * delta[i];
    }
  }

  for (int c = tid; c < 64 * 32; c += 256) {
    int e = c >> 5, s = c & 31;
    int n = n0 + e;
    if (n < NN) {
      if (s < 16) {
        *(uint4*)&sA[e][s * 8] = *((const uint4*)(nodeb + (size_t)n * 128) + s);
      } else {
        const float* p = m_agg + (size_t)n * 128 + (size_t)(s - 16) * 8;
        float4 v0 = *(const float4*)p;
        float4 v1 = *(const float4*)(p + 4);
        *(ushort4*)&sA[e][s * 8]     = make_ushort4(f2b(v0.x), f2b(v0.y), f2b(v0.z), f2b(v0.w));
        *(ushort4*)&sA[e][s * 8 + 4] = make_ushort4(f2b(v1.x), f2b(v1.y), f2b(v1.z), f2b(v1.w));
      }
    } else {
      *(uint4*)&sA[e][s * 8] = make_uint4(0, 0, 0, 0);
    }
  }
  __syncthreads();

  const int wave = tid >> 6, lane = tid & 63;
  const int quad = lane >> 4, l16 = lane & 15;
  const int col0 = wave * 32 + l16, col1 = wave * 32 + 16 + l16;

  const f32x4 zero = {0.f, 0.f, 0.f, 0.f};
  f32x4 acc[4][2];
#pragma unroll
  for (int mt = 0; mt < 4; mt++) { acc[mt][0] = zero; acc[mt][1] = zero; }

#pragma unroll
  for (int kt = 0; kt < 8; kt++) {
    int kb = kt * 32 + quad * 8;
    bf16x8 b0 = *(const bf16x8*)(Wh1T + (col0 << 8) + kb);
    bf16x8 b1 = *(const bf16x8*)(Wh1T + (col1 << 8) + kb);
#pragma unroll
    for (int mt = 0; mt < 4; mt++) {
      bf16x8 a = *(const bf16x8*)&sA[mt * 16 + l16][kb];
      acc[mt][0] = __builtin_amdgcn_mfma_f32_16x16x32_bf16(a, b0, acc[mt][0], 0, 0, 0);
      acc[mt][1] = __builtin_amdgcn_mfma_f32_16x16x32_bf16(a, b1, acc[mt][1], 0, 0, 0);
    }
  }

  {
    float sb0 = bh1[col0], sb1 = bh1[col1];
#pragma unroll
    for (int mt = 0; mt < 4; mt++) {
#pragma unroll
      for (int r = 0; r < 4; r++) {
        int row = mt * 16 + quad * 4 + r;
        sT[row][col0] = f2b(fmaxf(acc[mt][0][r] + sb0, 0.f));
        sT[row][col1] = f2b(fmaxf(acc[mt][1][r] + sb1, 0.f));
      }
    }
  }
  __syncthreads();

  f32x4 acc2[4][2];
#pragma unroll
  for (int mt = 0; mt < 4; mt++) { acc2[mt][0] = zero; acc2[mt][1] = zero; }
#pragma unroll
  for (int kt = 0; kt < 4; kt++) {
    int kb = kt * 32 + quad * 8;
    bf16x8 b0 = *(const bf16x8*)(Wh2T + (col0 << 7) + kb);
    bf16x8 b1 = *(const bf16x8*)(Wh2T + (col1 << 7) + kb);
#pragma unroll
    for (int mt = 0; mt < 4; mt++) {
      bf16x8 a = *(const bf16x8*)&sT[mt * 16 + l16][kb];
      acc2[mt][0] = __builtin_amdgcn_mfma_f32_16x16x32_bf16(a, b0, acc2[mt][0], 0, 0, 0);
      acc2[mt][1] = __builtin_amdgcn_mfma_f32_16x16x32_bf16(a, b1, acc2[mt][1], 0, 0, 0);
    }
  }

  {
    float eb0 = bh2[col0], eb1 = bh2[col1];
#pragma unroll
    for (int mt = 0; mt < 4; mt++) {
#pragma unroll
      for (int r = 0; r < 4; r++) {
        int row = mt * 16 + quad * 4 + r;
        int n = n0 + row;
        if (n < NN) {
          out[(size_t)n * 128 + col0] = acc2[mt][0][r] + eb0;
          out[(size_t)n * 128 + col1] = acc2[mt][1][r] + eb1;
        }
      }
    }
  }
}

extern "C" void kernel_launch(void* const* d_in, const int* in_sizes, int n_in,
                              void* d_out, int out_size, void* d_ws, size_t ws_size,
                              hipStream_t stream) {
  const float* node  = (const float*)d_in[0];
  const float* coord = (const float*)d_in[1];
  const int*   ei    = (const int*)d_in[2];
  const float* We1   = (const float*)d_in[3];
  const float* be1   = (const float*)d_in[4];
  const float* We2   = (const float*)d_in[5];
  const float* be2   = (const float*)d_in[6];
  const float* Wx    = (const float*)d_in[7];
  const float* bx    = (const float*)d_in[8];
  const float* Wh1   = (const float*)d_in[9];
  const float* bh1   = (const float*)d_in[10];
  const float* Wh2   = (const float*)d_in[11];
  const float* bh2   = (const float*)d_in[12];
  float* out = (float*)d_out;

  char* ws = (char*)d_ws;
  float* m_agg   = (float*)(ws);                      // 25,600,000
  float* delta   = (float*)(ws + 25600000);           //    600,000
  int*   cnt     = (int*)  (ws + 26200000);           //    200,704
  int*   starts  = (int*)  (ws + 26400704);           //    200,704
  int*   bsum    = (int*)  (ws + 26601408);           //      1,024
  int*   boffs   = (int*)  (ws + 26602432);           //      1,024
  int*   rank    = (int*)  (ws + 26603456);           //  3,200,000
  int*   order   = (int*)  (ws + 29803456);           //  3,200,000
  unsigned short* nodeb   = (unsigned short*)(ws + 33003456); // 12,800,000
  unsigned short* Yb      = (unsigned short*)(ws + 45803456); // 12,800,000
  unsigned short* We1Ttop = (unsigned short*)(ws + 58603456); //     32,768
  unsigned short* We1Tbot = (unsigned short*)(ws + 58636224); //     32,768
  unsigned short* We2T    = (unsigned short*)(ws + 58668992); //     32,768
  unsigned short* Wh1T    = (unsigned short*)(ws + 58701760); //     65,536
  unsigned short* Wh2T    = (unsigned short*)(ws + 58767296); //     32,768

  hipMemsetAsync(ws, 0, 26400704, stream);  // m_agg + delta + cnt

  cvt_node_kernel<<<6250, 256, 0, stream>>>(node, nodeb);
  prep_weights_kernel<<<384, 256, 0, stream>>>(We1, We2, Wh1, Wh2,
                                               We1Ttop, We1Tbot, We2T, Wh1T, Wh2T);
  hist_kernel<<<3125, 256, 0, stream>>>(ei, cnt, rank);
  scanA_kernel<<<196, 256, 0, stream>>>(cnt, bsum);
  scanB_kernel<<<1, 256, 0, stream>>>(bsum, boffs);
  scanC_kernel<<<196, 256, 0, stream>>>(cnt, boffs, starts);
  scatter_kernel<<<3125, 256, 0, stream>>>(ei, starts, rank, order);
  y_kernel<<<(NN + 63) / 64, 256, 0, stream>>>(nodeb, We1Ttop, be1, Yb);
  edge_kernel<<<NE / 64, 256, 0, stream>>>(nodeb, coord, ei, order, We1Tbot, We1,
                                           Yb, We2T, be2, Wx, bx, m_agg, delta);
  node_kernel<<<(NN + 63) / 64, 256, 0, stream>>>(nodeb, m_agg, Wh1T, bh1,
                                                  Wh2T, bh2, coord, delta, out);
}

// Round 4
// 303.384 us; speedup vs baseline: 2.1541x; 1.3036x over previous
//
#include <hip/hip_runtime.h>
#include <stdint.h>

#define NN 50000
#define NE 800000
#define NBINS 50001          // dst bins + 1 pad slot
#define H_OUT_OFF 6400000    // N*128, start of x_new in d_out

typedef float  f32x4  __attribute__((ext_vector_type(4)));
typedef short  bf16x8 __attribute__((ext_vector_type(8)));

static __device__ __forceinline__ unsigned short f2b(float f) {
  unsigned u = __float_as_uint(f);
  return (unsigned short)((u + 0x7fffu + ((u >> 16) & 1u)) >> 16);
}
static __device__ __forceinline__ float b2f(unsigned short h) {
  return __uint_as_float(((unsigned)h) << 16);
}

// ---- prep: node f32 -> bf16 ----
__global__ void cvt_node_kernel(const float* __restrict__ node,
                                unsigned short* __restrict__ nodeb) {
  int i = blockIdx.x * 256 + threadIdx.x;
  if (i < NN * 128 / 4) {
    float4 v = ((const float4*)node)[i];
    ((ushort4*)nodeb)[i] = make_ushort4(f2b(v.x), f2b(v.y), f2b(v.z), f2b(v.w));
  }
}

// ---- prep: weights -> bf16 transposed [n][k] ----
__global__ void prep_weights_kernel(const float* __restrict__ We1,
                                    const float* __restrict__ We2,
                                    const float* __restrict__ Wh1,
                                    const float* __restrict__ Wh2,
                                    unsigned short* __restrict__ We1Ttop,
                                    unsigned short* __restrict__ We1Tbot,
                                    unsigned short* __restrict__ We2T,
                                    unsigned short* __restrict__ Wh1T,
                                    unsigned short* __restrict__ Wh2T) {
  int i = blockIdx.x * 256 + threadIdx.x;
  if (i < 16384) {                       // We1Ttop [128n][128k], k = h_i dims
    int n = i >> 7, k = i & 127;
    We1Ttop[i] = f2b(We1[k * 128 + n]);
  } else if (i < 32768) {                // We1Tbot, k = h_j dims (rows 128..255)
    int j = i - 16384; int n = j >> 7, k = j & 127;
    We1Tbot[j] = f2b(We1[(128 + k) * 128 + n]);
  } else if (i < 49152) {                // We2T [128][128]
    int j = i - 32768; int n = j >> 7, k = j & 127;
    We2T[j] = f2b(We2[k * 128 + n]);
  } else if (i < 81920) {                // Wh1T [128][256]
    int j = i - 49152; int n = j >> 8, k = j & 255;
    Wh1T[j] = f2b(Wh1[k * 128 + n]);
  } else if (i < 98304) {                // Wh2T [128][128]
    int j = i - 81920; int n = j >> 7, k = j & 127;
    Wh2T[j] = f2b(Wh2[k * 128 + n]);
  }
}

// ---- u = We2 @ Wx (f32), c = be2.Wx + bx ----
__global__ void uc_kernel(const float* __restrict__ We2, const float* __restrict__ Wx,
                          const float* __restrict__ be2, const float* __restrict__ bx,
                          float* __restrict__ uvec) {
  int k = threadIdx.x;
  if (k < 128) {
    float s = 0.f;
    for (int n = 0; n < 128; n++) s += We2[k * 128 + n] * Wx[n];
    uvec[k] = s;
  } else if (k == 128) {
    float s = 0.f;
    for (int n = 0; n < 128; n++) s += be2[n] * Wx[n];
    uvec[128] = s + bx[0];
  }
}

// ---- counting sort of edges by dst ----
__global__ void hist_kernel(const int* __restrict__ ei, int* __restrict__ cnt,
                            int* __restrict__ rank) {
  int i = blockIdx.x * 256 + threadIdx.x;
  if (i < NE) rank[i] = atomicAdd(&cnt[ei[NE + i]], 1);
}

__global__ void scanA_kernel(const int* __restrict__ cnt, int* __restrict__ bsum) {
  __shared__ int sd[256];
  int b = blockIdx.x, t = threadIdx.x, i = b * 256 + t;
  sd[t] = (i < NBINS) ? cnt[i] : 0;
  __syncthreads();
  for (int s = 128; s; s >>= 1) {
    if (t < s) sd[t] += sd[t + s];
    __syncthreads();
  }
  if (t == 0) bsum[b] = sd[0];
}

__global__ void scanB_kernel(const int* __restrict__ bsum, int* __restrict__ boffs) {
  __shared__ int sd[256];
  int t = threadIdx.x;
  int v = (t < 196) ? bsum[t] : 0;
  sd[t] = v;
  __syncthreads();
  for (int off = 1; off < 256; off <<= 1) {
    int x = (t >= off) ? sd[t - off] : 0;
    __syncthreads();
    sd[t] += x;
    __syncthreads();
  }
  if (t < 196) boffs[t] = sd[t] - v;   // exclusive
}

__global__ void scanC_kernel(const int* __restrict__ cnt, const int* __restrict__ boffs,
                             int* __restrict__ starts) {
  __shared__ int sd[256];
  int b = blockIdx.x, t = threadIdx.x, i = b * 256 + t;
  int v = (i < NBINS) ? cnt[i] : 0;
  sd[t] = v;
  __syncthreads();
  for (int off = 1; off < 256; off <<= 1) {
    int x = (t >= off) ? sd[t - off] : 0;
    __syncthreads();
    sd[t] += x;
    __syncthreads();
  }
  if (i < NBINS) starts[i] = sd[t] - v + boffs[b];
}

__global__ void scatter_kernel(const int* __restrict__ ei, const int* __restrict__ starts,
                               const int* __restrict__ rank, int2* __restrict__ sdS) {
  int i = blockIdx.x * 256 + threadIdx.x;
  if (i < NE) {
    int s = ei[i], d = ei[NE + i];
    sdS[starts[d] + rank[i]] = make_int2(s, d);
  }
}

// ---- Y = node @ We1_top + be1 ; Z = node @ We1_bot (both bf16) ----
__global__ __launch_bounds__(256, 4)
void yz_kernel(const unsigned short* __restrict__ nodeb,
               const unsigned short* __restrict__ We1Ttop,
               const unsigned short* __restrict__ We1Tbot,
               const float* __restrict__ be1,
               unsigned short* __restrict__ Yb,
               unsigned short* __restrict__ Zb) {
  __shared__ __align__(16) unsigned short sA[64][136];
  const int tid = threadIdx.x;
  const int n0 = blockIdx.x * 64;

  for (int c = tid; c < 64 * 16; c += 256) {
    int e = c >> 4, s = c & 15;
    int n = n0 + e;
    if (n < NN) *(uint4*)&sA[e][s * 8] = *((const uint4*)(nodeb + (size_t)n * 128) + s);
    else        *(uint4*)&sA[e][s * 8] = make_uint4(0, 0, 0, 0);
  }
  __syncthreads();

  const int wave = tid >> 6, lane = tid & 63;
  const int quad = lane >> 4, l16 = lane & 15;
  const int col0 = wave * 32 + l16, col1 = wave * 32 + 16 + l16;

  const f32x4 zero = {0.f, 0.f, 0.f, 0.f};
  f32x4 accY[4][2], accZ[4][2];
#pragma unroll
  for (int mt = 0; mt < 4; mt++) {
    accY[mt][0] = zero; accY[mt][1] = zero;
    accZ[mt][0] = zero; accZ[mt][1] = zero;
  }

#pragma unroll
  for (int kt = 0; kt < 4; kt++) {
    int kb = kt * 32 + quad * 8;
    bf16x8 by0 = *(const bf16x8*)(We1Ttop + (col0 << 7) + kb);
    bf16x8 by1 = *(const bf16x8*)(We1Ttop + (col1 << 7) + kb);
    bf16x8 bz0 = *(const bf16x8*)(We1Tbot + (col0 << 7) + kb);
    bf16x8 bz1 = *(const bf16x8*)(We1Tbot + (col1 << 7) + kb);
#pragma unroll
    for (int mt = 0; mt < 4; mt++) {
      bf16x8 a = *(const bf16x8*)&sA[mt * 16 + l16][kb];
      accY[mt][0] = __builtin_amdgcn_mfma_f32_16x16x32_bf16(a, by0, accY[mt][0], 0, 0, 0);
      accY[mt][1] = __builtin_amdgcn_mfma_f32_16x16x32_bf16(a, by1, accY[mt][1], 0, 0, 0);
      accZ[mt][0] = __builtin_amdgcn_mfma_f32_16x16x32_bf16(a, bz0, accZ[mt][0], 0, 0, 0);
      accZ[mt][1] = __builtin_amdgcn_mfma_f32_16x16x32_bf16(a, bz1, accZ[mt][1], 0, 0, 0);
    }
  }

  float sb0 = be1[col0], sb1 = be1[col1];
#pragma unroll
  for (int mt = 0; mt < 4; mt++) {
#pragma unroll
    for (int r = 0; r < 4; r++) {
      int row = mt * 16 + quad * 4 + r;
      int n = n0 + row;
      if (n < NN) {
        Yb[(size_t)n * 128 + col0] = f2b(accY[mt][0][r] + sb0);
        Yb[(size_t)n * 128 + col1] = f2b(accY[mt][1][r] + sb1);
        Zb[(size_t)n * 128 + col0] = f2b(accZ[mt][0][r]);
        Zb[(size_t)n * 128 + col1] = f2b(accZ[mt][1][r]);
      }
    }
  }
}

// ---- edge kernel: NO MFMA. wave = 128 sorted edges, lane = 2 cols ----
// t = relu(Z[src] + Y[dst] + sq*wsq); accumulate T[dst] += t (register,
// flush on dst change); delta[dst] += (t.u + c)*dist via folded accumulators.
__global__ __launch_bounds__(256, 8)
void edge_kernel(const unsigned short* __restrict__ Zb,
                 const unsigned short* __restrict__ Yb,
                 const int2* __restrict__ sdS,
                 const float* __restrict__ coord,
                 const float* __restrict__ We1,   // row 256 = wsq
                 const float* __restrict__ uvec,  // u[0..127], c at [128]
                 float* __restrict__ T,
                 float* __restrict__ delta) {
  __shared__ int2   sSD[4][64];
  __shared__ float4 sQ[4][64];

  const int tid = threadIdx.x, wave = tid >> 6, lane = tid & 63;
  const int base = blockIdx.x * 512 + wave * 128;
  const int col = lane * 2;

  const float wsq0 = We1[256 * 128 + col], wsq1 = We1[256 * 128 + col + 1];
  const float u0 = uvec[col], u1 = uvec[col + 1];
  const float c  = uvec[128];

  float accT0 = 0.f, accT1 = 0.f;
  float sx = 0.f, sy = 0.f, sz = 0.f;          // sum of (t.u partial)*dist
  float dsx = 0.f, dsy = 0.f, dsz = 0.f;       // sum of dist (uniform)
  float y0 = 0.f, y1 = 0.f;
  int prev = -1;

  for (int ch = 0; ch < 2; ch++) {
    int cbase = base + ch * 64;
    if (cbase < NE) {                           // NE % 64 == 0: full chunks
      int2 sd = sdS[cbase + lane];
      float dx = coord[sd.y * 3 + 0] - coord[sd.x * 3 + 0];
      float dy = coord[sd.y * 3 + 1] - coord[sd.x * 3 + 1];
      float dz = coord[sd.y * 3 + 2] - coord[sd.x * 3 + 2];
      sSD[wave][lane] = sd;
      sQ[wave][lane] = make_float4(dx, dy, dz, dx * dx + dy * dy + dz * dz);
    }
    __syncthreads();
    if (cbase < NE) {
      for (int r = 0; r < 64; r++) {
        int2 sd = sSD[wave][r];                 // broadcast
        float4 q = sQ[wave][r];
        if (sd.y != prev) {                     // wave-uniform branch
          if (prev >= 0) {
            atomicAdd(&T[(size_t)prev * 128 + col],     accT0);
            atomicAdd(&T[(size_t)prev * 128 + col + 1], accT1);
            float rx = sx, ry = sy, rz = sz;
#pragma unroll
            for (int o = 1; o < 64; o <<= 1) {
              rx += __shfl_xor(rx, o); ry += __shfl_xor(ry, o); rz += __shfl_xor(rz, o);
            }
            if (lane == 0) {
              atomicAdd(&delta[prev * 3 + 0], rx + c * dsx);
              atomicAdd(&delta[prev * 3 + 1], ry + c * dsy);
              atomicAdd(&delta[prev * 3 + 2], rz + c * dsz);
            }
            accT0 = accT1 = sx = sy = sz = dsx = dsy = dsz = 0.f;
          }
          prev = sd.y;
          ushort2 yv = *(const ushort2*)&Yb[(size_t)sd.y * 128 + col];
          y0 = b2f(yv.x); y1 = b2f(yv.y);
        }
        ushort2 zv = *(const ushort2*)&Zb[(size_t)sd.x * 128 + col];
        float t0 = fmaxf(b2f(zv.x) + y0 + q.w * wsq0, 0.f);
        float t1 = fmaxf(b2f(zv.y) + y1 + q.w * wsq1, 0.f);
        accT0 += t0; accT1 += t1;
        float tu = t0 * u0 + t1 * u1;
        sx += tu * q.x; sy += tu * q.y; sz += tu * q.z;
        dsx += q.x; dsy += q.y; dsz += q.z;
      }
    }
    __syncthreads();
  }
  if (prev >= 0) {
    atomicAdd(&T[(size_t)prev * 128 + col],     accT0);
    atomicAdd(&T[(size_t)prev * 128 + col + 1], accT1);
    float rx = sx, ry = sy, rz = sz;
#pragma unroll
    for (int o = 1; o < 64; o <<= 1) {
      rx += __shfl_xor(rx, o); ry += __shfl_xor(ry, o); rz += __shfl_xor(rz, o);
    }
    if (lane == 0) {
      atomicAdd(&delta[prev * 3 + 0], rx + c * dsx);
      atomicAdd(&delta[prev * 3 + 1], ry + c * dsy);
      atomicAdd(&delta[prev * 3 + 2], rz + c * dsz);
    }
  }
}

// ---- node kernel: m = T@We2 + deg*be2, then phi_h, plus x_new ----
__global__ __launch_bounds__(256, 3)
void node_kernel(const unsigned short* __restrict__ nodeb,
                 const float* __restrict__ T,
                 const int* __restrict__ cnt,
                 const unsigned short* __restrict__ We2T,
                 const float* __restrict__ be2,
                 const unsigned short* __restrict__ Wh1T,
                 const float* __restrict__ bh1,
                 const unsigned short* __restrict__ Wh2T,
                 const float* __restrict__ bh2,
                 const float* __restrict__ coord,
                 const float* __restrict__ delta,
                 float* __restrict__ out) {
  __shared__ __align__(16) unsigned short sA[64][264];
  __shared__ __align__(16) unsigned short sT[64][136];
  __shared__ float sDeg[64];

  const int tid = threadIdx.x;
  const int n0 = blockIdx.x * 64;

  {
    int i = blockIdx.x * 192 + tid;
    if (tid < 192 && i < NN * 3) {
      out[H_OUT_OFF + i] = coord[i] + (1.0f / 49999.0f) * delta[i];
    }
  }
  if (tid < 64) {
    int n = n0 + tid;
    sDeg[tid] = (n < NN) ? (float)cnt[n] : 0.f;
  }

  // stage node bf16 -> sA cols 0..127 ; T f32 -> sT bf16
  for (int c = tid; c < 64 * 16; c += 256) {
    int e = c >> 4, s = c & 15;
    int n = n0 + e;
    if (n < NN) {
      *(uint4*)&sA[e][s * 8] = *((const uint4*)(nodeb + (size_t)n * 128) + s);
      const float* p = T + (size_t)n * 128 + s * 8;
      float4 v0 = *(const float4*)p;
      float4 v1 = *(const float4*)(p + 4);
      *(ushort4*)&sT[e][s * 8]     = make_ushort4(f2b(v0.x), f2b(v0.y), f2b(v0.z), f2b(v0.w));
      *(ushort4*)&sT[e][s * 8 + 4] = make_ushort4(f2b(v1.x), f2b(v1.y), f2b(v1.z), f2b(v1.w));
    } else {
      *(uint4*)&sA[e][s * 8] = make_uint4(0, 0, 0, 0);
      *(uint4*)&sT[e][s * 8] = make_uint4(0, 0, 0, 0);
    }
  }
  __syncthreads();

  const int wave = tid >> 6, lane = tid & 63;
  const int quad = lane >> 4, l16 = lane & 15;
  const int col0 = wave * 32 + l16, col1 = wave * 32 + 16 + l16;

  const f32x4 zero = {0.f, 0.f, 0.f, 0.f};

  // GEMM1: m = T @ We2 (K=128)
  f32x4 accM[4][2];
#pragma unroll
  for (int mt = 0; mt < 4; mt++) { accM[mt][0] = zero; accM[mt][1] = zero; }
#pragma unroll
  for (int kt = 0; kt < 4; kt++) {
    int kb = kt * 32 + quad * 8;
    bf16x8 b0 = *(const bf16x8*)(We2T + (col0 << 7) + kb);
    bf16x8 b1 = *(const bf16x8*)(We2T + (col1 << 7) + kb);
#pragma unroll
    for (int mt = 0; mt < 4; mt++) {
      bf16x8 a = *(const bf16x8*)&sT[mt * 16 + l16][kb];
      accM[mt][0] = __builtin_amdgcn_mfma_f32_16x16x32_bf16(a, b0, accM[mt][0], 0, 0, 0);
      accM[mt][1] = __builtin_amdgcn_mfma_f32_16x16x32_bf16(a, b1, accM[mt][1], 0, 0, 0);
    }
  }
  {
    float eb0 = be2[col0], eb1 = be2[col1];
#pragma unroll
    for (int mt = 0; mt < 4; mt++) {
#pragma unroll
      for (int r = 0; r < 4; r++) {
        int row = mt * 16 + quad * 4 + r;
        float dg = sDeg[row];
        sA[row][128 + col0] = f2b(accM[mt][0][r] + dg * eb0);
        sA[row][128 + col1] = f2b(accM[mt][1][r] + dg * eb1);
      }
    }
  }
  __syncthreads();

  // GEMM2: [node|m] @ Wh1 (K=256), relu -> sT
  f32x4 acc[4][2];
#pragma unroll
  for (int mt = 0; mt < 4; mt++) { acc[mt][0] = zero; acc[mt][1] = zero; }
#pragma unroll
  for (int kt = 0; kt < 8; kt++) {
    int kb = kt * 32 + quad * 8;
    bf16x8 b0 = *(const bf16x8*)(Wh1T + (col0 << 8) + kb);
    bf16x8 b1 = *(const bf16x8*)(Wh1T + (col1 << 8) + kb);
#pragma unroll
    for (int mt = 0; mt < 4; mt++) {
      bf16x8 a = *(const bf16x8*)&sA[mt * 16 + l16][kb];
      acc[mt][0] = __builtin_amdgcn_mfma_f32_16x16x32_bf16(a, b0, acc[mt][0], 0, 0, 0);
      acc[mt][1] = __builtin_amdgcn_mfma_f32_16x16x32_bf16(a, b1, acc[mt][1], 0, 0, 0);
    }
  }
  {
    float sb0 = bh1[col0], sb1 = bh1[col1];
#pragma unroll
    for (int mt = 0; mt < 4; mt++) {
#pragma unroll
      for (int r = 0; r < 4; r++) {
        int row = mt * 16 + quad * 4 + r;
        sT[row][col0] = f2b(fmaxf(acc[mt][0][r] + sb0, 0.f));
        sT[row][col1] = f2b(fmaxf(acc[mt][1][r] + sb1, 0.f));
      }
    }
  }
  __syncthreads();

  // GEMM3: @ Wh2 (K=128) -> out
  f32x4 acc2[4][2];
#pragma unroll
  for (int mt = 0; mt < 4; mt++) { acc2[mt][0] = zero; acc2[mt][1] = zero; }
#pragma unroll
  for (int kt = 0; kt < 4; kt++) {
    int kb = kt * 32 + quad * 8;
    bf16x8 b0 = *(const bf16x8*)(Wh2T + (col0 << 7) + kb);
    bf16x8 b1 = *(const bf16x8*)(Wh2T + (col1 << 7) + kb);
#pragma unroll
    for (int mt = 0; mt < 4; mt++) {
      bf16x8 a = *(const bf16x8*)&sT[mt * 16 + l16][kb];
      acc2[mt][0] = __builtin_amdgcn_mfma_f32_16x16x32_bf16(a, b0, acc2[mt][0], 0, 0, 0);
      acc2[mt][1] = __builtin_amdgcn_mfma_f32_16x16x32_bf16(a, b1, acc2[mt][1], 0, 0, 0);
    }
  }
  {
    float eb0 = bh2[col0], eb1 = bh2[col1];
#pragma unroll
    for (int mt = 0; mt < 4; mt++) {
#pragma unroll
      for (int r = 0; r < 4; r++) {
        int row = mt * 16 + quad * 4 + r;
        int n = n0 + row;
        if (n < NN) {
          out[(size_t)n * 128 + col0] = acc2[mt][0][r] + eb0;
          out[(size_t)n * 128 + col1] = acc2[mt][1][r] + eb1;
        }
      }
    }
  }
}

extern "C" void kernel_launch(void* const* d_in, const int* in_sizes, int n_in,
                              void* d_out, int out_size, void* d_ws, size_t ws_size,
                              hipStream_t stream) {
  const float* node  = (const float*)d_in[0];
  const float* coord = (const float*)d_in[1];
  const int*   ei    = (const int*)d_in[2];
  const float* We1   = (const float*)d_in[3];
  const float* be1   = (const float*)d_in[4];
  const float* We2   = (const float*)d_in[5];
  const float* be2   = (const float*)d_in[6];
  const float* Wx    = (const float*)d_in[7];
  const float* bx    = (const float*)d_in[8];
  const float* Wh1   = (const float*)d_in[9];
  const float* bh1   = (const float*)d_in[10];
  const float* Wh2   = (const float*)d_in[11];
  const float* bh2   = (const float*)d_in[12];
  float* out = (float*)d_out;

  char* ws = (char*)d_ws;
  float* T       = (float*)(ws);                      // 25,600,000
  float* delta   = (float*)(ws + 25600000);           //    600,000
  int*   cnt     = (int*)  (ws + 26200000);           //    200,704
  int*   starts  = (int*)  (ws + 26400704);           //    200,704
  int*   bsum    = (int*)  (ws + 26601408);           //      1,024
  int*   boffs   = (int*)  (ws + 26602432);           //      1,024
  int2*  sdS     = (int2*) (ws + 26603456);           //  6,400,000
  unsigned short* nodeb   = (unsigned short*)(ws + 33003456); // 12,800,000
  unsigned short* Yb      = (unsigned short*)(ws + 45803456); // 12,800,000
  unsigned short* Zb      = (unsigned short*)(ws + 58603456); // 12,800,000
  int*   rank    = (int*)  (ws + 58603456);           // overlaps Zb (dead before yz)
  unsigned short* We1Ttop = (unsigned short*)(ws + 71403456); //     32,768
  unsigned short* We1Tbot = (unsigned short*)(ws + 71436224); //     32,768
  unsigned short* We2T    = (unsigned short*)(ws + 71468992); //     32,768
  unsigned short* Wh1T    = (unsigned short*)(ws + 71501760); //     65,536
  unsigned short* Wh2T    = (unsigned short*)(ws + 71567296); //     32,768
  float* uvec    = (float*)(ws + 71600064);           //        516

  hipMemsetAsync(ws, 0, 26400704, stream);  // T + delta + cnt

  cvt_node_kernel<<<6250, 256, 0, stream>>>(node, nodeb);
  prep_weights_kernel<<<384, 256, 0, stream>>>(We1, We2, Wh1, Wh2,
                                               We1Ttop, We1Tbot, We2T, Wh1T, Wh2T);
  uc_kernel<<<1, 192, 0, stream>>>(We2, Wx, be2, bx, uvec);
  hist_kernel<<<3125, 256, 0, stream>>>(ei, cnt, rank);
  scanA_kernel<<<196, 256, 0, stream>>>(cnt, bsum);
  scanB_kernel<<<1, 256, 0, stream>>>(bsum, boffs);
  scanC_kernel<<<196, 256, 0, stream>>>(cnt, boffs, starts);
  scatter_kernel<<<3125, 256, 0, stream>>>(ei, starts, rank, sdS);
  yz_kernel<<<(NN + 63) / 64, 256, 0, stream>>>(nodeb, We1Ttop, We1Tbot, be1, Yb, Zb);
  edge_kernel<<<(NE + 511) / 512, 256, 0, stream>>>(Zb, Yb, sdS, coord, We1, uvec,
                                                    T, delta);
  node_kernel<<<(NN + 63) / 64, 256, 0, stream>>>(nodeb, T, cnt, We2T, be2,
                                                  Wh1T, bh1, Wh2T, bh2,
                                                  coord, delta, out);
}

// Round 5
// 274.330 us; speedup vs baseline: 2.3823x; 1.1059x over previous
//
#include <hip/hip_runtime.h>
#include <stdint.h>

#define NN 50000
#define NE 800000
#define NBINS 50001          // dst bins + 1 pad slot
#define H_OUT_OFF 6400000    // N*128, start of x_new in d_out

typedef float  f32x4  __attribute__((ext_vector_type(4)));
typedef short  bf16x8 __attribute__((ext_vector_type(8)));

static __device__ __forceinline__ unsigned short f2b(float f) {
  unsigned u = __float_as_uint(f);
  return (unsigned short)((u + 0x7fffu + ((u >> 16) & 1u)) >> 16);
}
static __device__ __forceinline__ float b2f(unsigned short h) {
  return __uint_as_float(((unsigned)h) << 16);
}

// ---- prep: weights -> bf16 transposed [n][k] ----
__global__ void prep_weights_kernel(const float* __restrict__ We1,
                                    const float* __restrict__ We2,
                                    const float* __restrict__ Wh1,
                                    const float* __restrict__ Wh2,
                                    unsigned short* __restrict__ We1Ttop,
                                    unsigned short* __restrict__ We1Tbot,
                                    unsigned short* __restrict__ We2T,
                                    unsigned short* __restrict__ Wh1T,
                                    unsigned short* __restrict__ Wh2T) {
  int i = blockIdx.x * 256 + threadIdx.x;
  if (i < 16384) {                       // We1Ttop [128n][128k], k = h_i dims
    int n = i >> 7, k = i & 127;
    We1Ttop[i] = f2b(We1[k * 128 + n]);
  } else if (i < 32768) {                // We1Tbot, k = h_j dims (rows 128..255)
    int j = i - 16384; int n = j >> 7, k = j & 127;
    We1Tbot[j] = f2b(We1[(128 + k) * 128 + n]);
  } else if (i < 49152) {                // We2T [128][128]
    int j = i - 32768; int n = j >> 7, k = j & 127;
    We2T[j] = f2b(We2[k * 128 + n]);
  } else if (i < 81920) {                // Wh1T [128][256]
    int j = i - 49152; int n = j >> 8, k = j & 255;
    Wh1T[j] = f2b(Wh1[k * 128 + n]);
  } else if (i < 98304) {                // Wh2T [128][128]
    int j = i - 81920; int n = j >> 7, k = j & 127;
    Wh2T[j] = f2b(Wh2[k * 128 + n]);
  }
}

// ---- u = We2 @ Wx (f32), c = be2.Wx + bx ----
__global__ void uc_kernel(const float* __restrict__ We2, const float* __restrict__ Wx,
                          const float* __restrict__ be2, const float* __restrict__ bx,
                          float* __restrict__ uvec) {
  int k = threadIdx.x;
  if (k < 128) {
    float s = 0.f;
    for (int n = 0; n < 128; n++) s += We2[k * 128 + n] * Wx[n];
    uvec[k] = s;
  } else if (k == 128) {
    float s = 0.f;
    for (int n = 0; n < 128; n++) s += be2[n] * Wx[n];
    uvec[128] = s + bx[0];
  }
}

// ---- counting sort of edges by dst ----
__global__ void hist_kernel(const int* __restrict__ ei, int* __restrict__ cnt,
                            int* __restrict__ rank) {
  int i = blockIdx.x * 256 + threadIdx.x;
  if (i < NE) rank[i] = atomicAdd(&cnt[ei[NE + i]], 1);
}

__global__ void scanA_kernel(const int* __restrict__ cnt, int* __restrict__ bsum) {
  __shared__ int sd[256];
  int b = blockIdx.x, t = threadIdx.x, i = b * 256 + t;
  sd[t] = (i < NBINS) ? cnt[i] : 0;
  __syncthreads();
  for (int s = 128; s; s >>= 1) {
    if (t < s) sd[t] += sd[t + s];
    __syncthreads();
  }
  if (t == 0) bsum[b] = sd[0];
}

__global__ void scanB_kernel(const int* __restrict__ bsum, int* __restrict__ boffs) {
  __shared__ int sd[256];
  int t = threadIdx.x;
  int v = (t < 196) ? bsum[t] : 0;
  sd[t] = v;
  __syncthreads();
  for (int off = 1; off < 256; off <<= 1) {
    int x = (t >= off) ? sd[t - off] : 0;
    __syncthreads();
    sd[t] += x;
    __syncthreads();
  }
  if (t < 196) boffs[t] = sd[t] - v;   // exclusive
}

__global__ void scanC_kernel(const int* __restrict__ cnt, const int* __restrict__ boffs,
                             int* __restrict__ starts) {
  __shared__ int sd[256];
  int b = blockIdx.x, t = threadIdx.x, i = b * 256 + t;
  int v = (i < NBINS) ? cnt[i] : 0;
  sd[t] = v;
  __syncthreads();
  for (int off = 1; off < 256; off <<= 1) {
    int x = (t >= off) ? sd[t - off] : 0;
    __syncthreads();
    sd[t] += x;
    __syncthreads();
  }
  if (i < NBINS) starts[i] = sd[t] - v + boffs[b];
}

__global__ void scatter_kernel(const int* __restrict__ ei, const int* __restrict__ starts,
                               const int* __restrict__ rank, int* __restrict__ srcs) {
  int i = blockIdx.x * 256 + threadIdx.x;
  if (i < NE) {
    srcs[starts[ei[NE + i]] + rank[i]] = ei[i];
  }
}

// ---- Y = node @ We1_top + be1 ; Z = node @ We1_bot (both bf16) ----
__global__ __launch_bounds__(256, 4)
void yz_kernel(const float* __restrict__ node,
               const unsigned short* __restrict__ We1Ttop,
               const unsigned short* __restrict__ We1Tbot,
               const float* __restrict__ be1,
               unsigned short* __restrict__ Yb,
               unsigned short* __restrict__ Zb) {
  __shared__ __align__(16) unsigned short sA[64][136];
  const int tid = threadIdx.x;
  const int n0 = blockIdx.x * 64;

  for (int c = tid; c < 64 * 16; c += 256) {
    int e = c >> 4, s = c & 15;
    int n = n0 + e;
    if (n < NN) {
      const float* p = node + (size_t)n * 128 + s * 8;
      float4 v0 = *(const float4*)p;
      float4 v1 = *(const float4*)(p + 4);
      *(ushort4*)&sA[e][s * 8]     = make_ushort4(f2b(v0.x), f2b(v0.y), f2b(v0.z), f2b(v0.w));
      *(ushort4*)&sA[e][s * 8 + 4] = make_ushort4(f2b(v1.x), f2b(v1.y), f2b(v1.z), f2b(v1.w));
    } else {
      *(uint4*)&sA[e][s * 8] = make_uint4(0, 0, 0, 0);
    }
  }
  __syncthreads();

  const int wave = tid >> 6, lane = tid & 63;
  const int quad = lane >> 4, l16 = lane & 15;
  const int col0 = wave * 32 + l16, col1 = wave * 32 + 16 + l16;

  const f32x4 zero = {0.f, 0.f, 0.f, 0.f};
  f32x4 accY[4][2], accZ[4][2];
#pragma unroll
  for (int mt = 0; mt < 4; mt++) {
    accY[mt][0] = zero; accY[mt][1] = zero;
    accZ[mt][0] = zero; accZ[mt][1] = zero;
  }

#pragma unroll
  for (int kt = 0; kt < 4; kt++) {
    int kb = kt * 32 + quad * 8;
    bf16x8 by0 = *(const bf16x8*)(We1Ttop + (col0 << 7) + kb);
    bf16x8 by1 = *(const bf16x8*)(We1Ttop + (col1 << 7) + kb);
    bf16x8 bz0 = *(const bf16x8*)(We1Tbot + (col0 << 7) + kb);
    bf16x8 bz1 = *(const bf16x8*)(We1Tbot + (col1 << 7) + kb);
#pragma unroll
    for (int mt = 0; mt < 4; mt++) {
      bf16x8 a = *(const bf16x8*)&sA[mt * 16 + l16][kb];
      accY[mt][0] = __builtin_amdgcn_mfma_f32_16x16x32_bf16(a, by0, accY[mt][0], 0, 0, 0);
      accY[mt][1] = __builtin_amdgcn_mfma_f32_16x16x32_bf16(a, by1, accY[mt][1], 0, 0, 0);
      accZ[mt][0] = __builtin_amdgcn_mfma_f32_16x16x32_bf16(a, bz0, accZ[mt][0], 0, 0, 0);
      accZ[mt][1] = __builtin_amdgcn_mfma_f32_16x16x32_bf16(a, bz1, accZ[mt][1], 0, 0, 0);
    }
  }

  float sb0 = be1[col0], sb1 = be1[col1];
#pragma unroll
  for (int mt = 0; mt < 4; mt++) {
#pragma unroll
    for (int r = 0; r < 4; r++) {
      int row = mt * 16 + quad * 4 + r;
      int n = n0 + row;
      if (n < NN) {
        Yb[(size_t)n * 128 + col0] = f2b(accY[mt][0][r] + sb0);
        Yb[(size_t)n * 128 + col1] = f2b(accY[mt][1][r] + sb1);
        Zb[(size_t)n * 128 + col0] = f2b(accZ[mt][0][r]);
        Zb[(size_t)n * 128 + col1] = f2b(accZ[mt][1][r]);
      }
    }
  }
}

// ---- edge kernel: wave = one dst node (CSR). No atomics, no MFMA. ----
// T[n] = sum_e relu(Z[src_e] + Y[n] + sq_e*wsq)  (plain store)
// x_new[n] = coord[n] + C * sum_e (t_e.u + c)*dist_e  (folded, plain store)
__global__ __launch_bounds__(256, 8)
void edge_kernel(const unsigned short* __restrict__ Zb,
                 const unsigned short* __restrict__ Yb,
                 const int* __restrict__ srcs,
                 const int* __restrict__ starts,
                 const float* __restrict__ coord,
                 const float* __restrict__ We1,   // row 256 = wsq
                 const float* __restrict__ uvec,  // u[0..127], c at [128]
                 float* __restrict__ T,
                 float* __restrict__ out) {
  __shared__ int    sSrc[4][64];
  __shared__ float4 sQ[4][64];
  __shared__ int    sMaxChunks;

  const int tid = threadIdx.x, wave = tid >> 6, lane = tid & 63;
  const int n = blockIdx.x * 4 + wave;        // dst node; grid covers NN exactly
  const int col = lane * 2;

  const int start = starts[n], end = starts[n + 1];
  const int deg = end - start;
  const int chunks = (deg + 63) >> 6;

  if (tid == 0) sMaxChunks = 0;
  __syncthreads();
  if (lane == 0) atomicMax(&sMaxChunks, chunks);
  __syncthreads();
  const int nch = sMaxChunks;

  const float wsq0 = We1[256 * 128 + col], wsq1 = We1[256 * 128 + col + 1];
  const float u0 = uvec[col], u1 = uvec[col + 1];
  const float c  = uvec[128];

  ushort2 yv = *(const ushort2*)&Yb[(size_t)n * 128 + col];
  const float y0 = b2f(yv.x), y1 = b2f(yv.y);
  const float cdx = coord[n * 3 + 0], cdy = coord[n * 3 + 1], cdz = coord[n * 3 + 2];

  float accT0 = 0.f, accT1 = 0.f;
  float sx = 0.f, sy = 0.f, sz = 0.f;    // per-lane partial of (t.u)*dist
  float dsx = 0.f, dsy = 0.f, dsz = 0.f; // per-lane partial of dist

  for (int ch = 0; ch < nch; ch++) {
    int cb = start + ch * 64;
    int m = end - cb; if (m > 64) m = 64;
    if (lane < m) {
      int s = srcs[cb + lane];
      float dx = cdx - coord[s * 3 + 0];
      float dy = cdy - coord[s * 3 + 1];
      float dz = cdz - coord[s * 3 + 2];
      sSrc[wave][lane] = s;
      sQ[wave][lane] = make_float4(dx, dy, dz, dx * dx + dy * dy + dz * dz);
      dsx += dx; dsy += dy; dsz += dz;
    }
    __syncthreads();
#pragma unroll 4
    for (int r = 0; r < m; r++) {
      int ss = sSrc[wave][r];
      float4 q = sQ[wave][r];
      float tmp0 = y0 + q.w * wsq0;
      float tmp1 = y1 + q.w * wsq1;
      ushort2 zv = *(const ushort2*)&Zb[(size_t)ss * 128 + col];
      float t0 = fmaxf(b2f(zv.x) + tmp0, 0.f);
      float t1 = fmaxf(b2f(zv.y) + tmp1, 0.f);
      accT0 += t0; accT1 += t1;
      float tu = t0 * u0 + t1 * u1;
      sx += tu * q.x; sy += tu * q.y; sz += tu * q.z;
    }
    __syncthreads();
  }

  // plain store of T row (this wave owns node n)
  *(float2*)&T[(size_t)n * 128 + col] = make_float2(accT0, accT1);

  // fold c*dist before reduction, then butterfly over 64 lanes
  float px = sx + c * dsx, py = sy + c * dsy, pz = sz + c * dsz;
#pragma unroll
  for (int o = 1; o < 64; o <<= 1) {
    px += __shfl_xor(px, o); py += __shfl_xor(py, o); pz += __shfl_xor(pz, o);
  }
  if (lane == 0) {
    const float C = 1.0f / 49999.0f;
    out[H_OUT_OFF + n * 3 + 0] = cdx + C * px;
    out[H_OUT_OFF + n * 3 + 1] = cdy + C * py;
    out[H_OUT_OFF + n * 3 + 2] = cdz + C * pz;
  }
}

// ---- node kernel: m = T@We2 + deg*be2, then phi_h ----
__global__ __launch_bounds__(256, 3)
void node_kernel(const float* __restrict__ node,
                 const float* __restrict__ T,
                 const int* __restrict__ starts,
                 const unsigned short* __restrict__ We2T,
                 const float* __restrict__ be2,
                 const unsigned short* __restrict__ Wh1T,
                 const float* __restrict__ bh1,
                 const unsigned short* __restrict__ Wh2T,
                 const float* __restrict__ bh2,
                 float* __restrict__ out) {
  __shared__ __align__(16) unsigned short sA[64][264];
  __shared__ __align__(16) unsigned short sT[64][136];
  __shared__ float sDeg[64];

  const int tid = threadIdx.x;
  const int n0 = blockIdx.x * 64;

  if (tid < 64) {
    int n = n0 + tid;
    sDeg[tid] = (n < NN) ? (float)(starts[n + 1] - starts[n]) : 0.f;
  }

  // stage node f32->bf16 -> sA cols 0..127 ; T f32->bf16 -> sT
  for (int c = tid; c < 64 * 16; c += 256) {
    int e = c >> 4, s = c & 15;
    int n = n0 + e;
    if (n < NN) {
      const float* pn = node + (size_t)n * 128 + s * 8;
      float4 a0 = *(const float4*)pn;
      float4 a1 = *(const float4*)(pn + 4);
      *(ushort4*)&sA[e][s * 8]     = make_ushort4(f2b(a0.x), f2b(a0.y), f2b(a0.z), f2b(a0.w));
      *(ushort4*)&sA[e][s * 8 + 4] = make_ushort4(f2b(a1.x), f2b(a1.y), f2b(a1.z), f2b(a1.w));
      const float* p = T + (size_t)n * 128 + s * 8;
      float4 v0 = *(const float4*)p;
      float4 v1 = *(const float4*)(p + 4);
      *(ushort4*)&sT[e][s * 8]     = make_ushort4(f2b(v0.x), f2b(v0.y), f2b(v0.z), f2b(v0.w));
      *(ushort4*)&sT[e][s * 8 + 4] = make_ushort4(f2b(v1.x), f2b(v1.y), f2b(v1.z), f2b(v1.w));
    } else {
      *(uint4*)&sA[e][s * 8] = make_uint4(0, 0, 0, 0);
      *(uint4*)&sT[e][s * 8] = make_uint4(0, 0, 0, 0);
    }
  }
  __syncthreads();

  const int wave = tid >> 6, lane = tid & 63;
  const int quad = lane >> 4, l16 = lane & 15;
  const int col0 = wave * 32 + l16, col1 = wave * 32 + 16 + l16;

  const f32x4 zero = {0.f, 0.f, 0.f, 0.f};

  // GEMM1: m = T @ We2 (K=128)
  f32x4 accM[4][2];
#pragma unroll
  for (int mt = 0; mt < 4; mt++) { accM[mt][0] = zero; accM[mt][1] = zero; }
#pragma unroll
  for (int kt = 0; kt < 4; kt++) {
    int kb = kt * 32 + quad * 8;
    bf16x8 b0 = *(const bf16x8*)(We2T + (col0 << 7) + kb);
    bf16x8 b1 = *(const bf16x8*)(We2T + (col1 << 7) + kb);
#pragma unroll
    for (int mt = 0; mt < 4; mt++) {
      bf16x8 a = *(const bf16x8*)&sT[mt * 16 + l16][kb];
      accM[mt][0] = __builtin_amdgcn_mfma_f32_16x16x32_bf16(a, b0, accM[mt][0], 0, 0, 0);
      accM[mt][1] = __builtin_amdgcn_mfma_f32_16x16x32_bf16(a, b1, accM[mt][1], 0, 0, 0);
    }
  }
  {
    float eb0 = be2[col0], eb1 = be2[col1];
#pragma unroll
    for (int mt = 0; mt < 4; mt++) {
#pragma unroll
      for (int r = 0; r < 4; r++) {
        int row = mt * 16 + quad * 4 + r;
        float dg = sDeg[row];
        sA[row][128 + col0] = f2b(accM[mt][0][r] + dg * eb0);
        sA[row][128 + col1] = f2b(accM[mt][1][r] + dg * eb1);
      }
    }
  }
  __syncthreads();

  // GEMM2: [node|m] @ Wh1 (K=256), relu -> sT
  f32x4 acc[4][2];
#pragma unroll
  for (int mt = 0; mt < 4; mt++) { acc[mt][0] = zero; acc[mt][1] = zero; }
#pragma unroll
  for (int kt = 0; kt < 8; kt++) {
    int kb = kt * 32 + quad * 8;
    bf16x8 b0 = *(const bf16x8*)(Wh1T + (col0 << 8) + kb);
    bf16x8 b1 = *(const bf16x8*)(Wh1T + (col1 << 8) + kb);
#pragma unroll
    for (int mt = 0; mt < 4; mt++) {
      bf16x8 a = *(const bf16x8*)&sA[mt * 16 + l16][kb];
      acc[mt][0] = __builtin_amdgcn_mfma_f32_16x16x32_bf16(a, b0, acc[mt][0], 0, 0, 0);
      acc[mt][1] = __builtin_amdgcn_mfma_f32_16x16x32_bf16(a, b1, acc[mt][1], 0, 0, 0);
    }
  }
  {
    float sb0 = bh1[col0], sb1 = bh1[col1];
#pragma unroll
    for (int mt = 0; mt < 4; mt++) {
#pragma unroll
      for (int r = 0; r < 4; r++) {
        int row = mt * 16 + quad * 4 + r;
        sT[row][col0] = f2b(fmaxf(acc[mt][0][r] + sb0, 0.f));
        sT[row][col1] = f2b(fmaxf(acc[mt][1][r] + sb1, 0.f));
      }
    }
  }
  __syncthreads();

  // GEMM3: @ Wh2 (K=128) -> out
  f32x4 acc2[4][2];
#pragma unroll
  for (int mt = 0; mt < 4; mt++) { acc2[mt][0] = zero; acc2[mt][1] = zero; }
#pragma unroll
  for (int kt = 0; kt < 4; kt++) {
    int kb = kt * 32 + quad * 8;
    bf16x8 b0 = *(const bf16x8*)(Wh2T + (col0 << 7) + kb);
    bf16x8 b1 = *(const bf16x8*)(Wh2T + (col1 << 7) + kb);
#pragma unroll
    for (int mt = 0; mt < 4; mt++) {
      bf16x8 a = *(const bf16x8*)&sT[mt * 16 + l16][kb];
      acc2[mt][0] = __builtin_amdgcn_mfma_f32_16x16x32_bf16(a, b0, acc2[mt][0], 0, 0, 0);
      acc2[mt][1] = __builtin_amdgcn_mfma_f32_16x16x32_bf16(a, b1, acc2[mt][1], 0, 0, 0);
    }
  }
  {
    float eb0 = bh2[col0], eb1 = bh2[col1];
#pragma unroll
    for (int mt = 0; mt < 4; mt++) {
#pragma unroll
      for (int r = 0; r < 4; r++) {
        int row = mt * 16 + quad * 4 + r;
        int n = n0 + row;
        if (n < NN) {
          out[(size_t)n * 128 + col0] = acc2[mt][0][r] + eb0;
          out[(size_t)n * 128 + col1] = acc2[mt][1][r] + eb1;
        }
      }
    }
  }
}

extern "C" void kernel_launch(void* const* d_in, const int* in_sizes, int n_in,
                              void* d_out, int out_size, void* d_ws, size_t ws_size,
                              hipStream_t stream) {
  const float* node  = (const float*)d_in[0];
  const float* coord = (const float*)d_in[1];
  const int*   ei    = (const int*)d_in[2];
  const float* We1   = (const float*)d_in[3];
  const float* be1   = (const float*)d_in[4];
  const float* We2   = (const float*)d_in[5];
  const float* be2   = (const float*)d_in[6];
  const float* Wx    = (const float*)d_in[7];
  const float* bx    = (const float*)d_in[8];
  const float* Wh1   = (const float*)d_in[9];
  const float* bh1   = (const float*)d_in[10];
  const float* Wh2   = (const float*)d_in[11];
  const float* bh2   = (const float*)d_in[12];
  float* out = (float*)d_out;

  char* ws = (char*)d_ws;
  float* T       = (float*)(ws);                      // 25,600,000
  int*   cnt     = (int*)  (ws + 25600000);           //    200,704
  int*   starts  = (int*)  (ws + 25800704);           //    200,704
  int*   bsum    = (int*)  (ws + 26001408);           //      1,024
  int*   boffs   = (int*)  (ws + 26002432);           //      1,024
  int*   rank    = (int*)  (ws + 26003456);           //  3,200,000
  int*   srcs    = (int*)  (ws + 29203456);           //  3,200,000
  unsigned short* Yb      = (unsigned short*)(ws + 32403456); // 12,800,000
  unsigned short* Zb      = (unsigned short*)(ws + 45203456); // 12,800,000
  unsigned short* We1Ttop = (unsigned short*)(ws + 58003456); //     32,768
  unsigned short* We1Tbot = (unsigned short*)(ws + 58036224); //     32,768
  unsigned short* We2T    = (unsigned short*)(ws + 58068992); //     32,768
  unsigned short* Wh1T    = (unsigned short*)(ws + 58101760); //     65,536
  unsigned short* Wh2T    = (unsigned short*)(ws + 58167296); //     32,768
  float* uvec    = (float*)(ws + 58200064);           //        516

  hipMemsetAsync(cnt, 0, 200704, stream);   // only the histogram needs zeroing

  prep_weights_kernel<<<384, 256, 0, stream>>>(We1, We2, Wh1, Wh2,
                                               We1Ttop, We1Tbot, We2T, Wh1T, Wh2T);
  uc_kernel<<<1, 192, 0, stream>>>(We2, Wx, be2, bx, uvec);
  hist_kernel<<<3125, 256, 0, stream>>>(ei, cnt, rank);
  scanA_kernel<<<196, 256, 0, stream>>>(cnt, bsum);
  scanB_kernel<<<1, 256, 0, stream>>>(bsum, boffs);
  scanC_kernel<<<196, 256, 0, stream>>>(cnt, boffs, starts);
  scatter_kernel<<<3125, 256, 0, stream>>>(ei, starts, rank, srcs);
  yz_kernel<<<(NN + 63) / 64, 256, 0, stream>>>(node, We1Ttop, We1Tbot, be1, Yb, Zb);
  edge_kernel<<<NN / 4, 256, 0, stream>>>(Zb, Yb, srcs, starts, coord, We1, uvec,
                                          T, out);
  node_kernel<<<(NN + 63) / 64, 256, 0, stream>>>(node, T, starts, We2T, be2,
                                                  Wh1T, bh1, Wh2T, bh2, out);
}